// Round 1
// baseline (10633.360 us; speedup 1.0000x reference)
//
#include <hip/hip_runtime.h>
#include <cmath>

// ---------------------------------------------------------------------------
// VQ-VAE forward, fp32 direct implementation.
// B=256, C=3, HW=64, D=256, K=8192, LAT=128
// BN is training-mode over (B,H,W); normalization is FUSED into the consumer
// kernel's input read (saves a full pass per layer).
// ---------------------------------------------------------------------------

#define EPS_BN 1e-5f

__device__ __forceinline__ float lrelu(float v) { return v >= 0.f ? v : 0.01f * v; }

// ---- direct conv 3x3, stride 2, pad 1, + bias + LeakyReLU ----------------
// weight layout (COUT, CIN, 3, 3). Optional per-channel input norm (nm/ns).
template <int CIN, int HIN, int COUT>
__global__ __launch_bounds__(256) void conv_s2_lrelu(
    const float* __restrict__ x, const float* __restrict__ w,
    const float* __restrict__ bias, const float* __restrict__ nm,
    const float* __restrict__ ns, float* __restrict__ y) {
  constexpr int HOUT = HIN / 2;
  int i = blockIdx.x * 256 + threadIdx.x;
  int ox = i % HOUT;
  int t = i / HOUT;
  int oy = t % HOUT;
  t /= HOUT;
  int co = t % COUT;
  int n = t / COUT;
  float acc = bias[co];
  const float* xn = x + (size_t)n * CIN * HIN * HIN;
  const float* wc = w + (size_t)co * CIN * 9;
  const int iy0 = oy * 2 - 1, ix0 = ox * 2 - 1;
  for (int ci = 0; ci < CIN; ++ci) {
    const float* xp = xn + (size_t)ci * HIN * HIN;
    const float* wp = wc + ci * 9;
    const float m = nm ? nm[ci] : 0.f;
    const float s = ns ? ns[ci] : 1.f;
#pragma unroll
    for (int ky = 0; ky < 3; ++ky) {
      const int iy = iy0 + ky;
      if ((unsigned)iy >= (unsigned)HIN) continue;
#pragma unroll
      for (int kx = 0; kx < 3; ++kx) {
        const int ix = ix0 + kx;
        if ((unsigned)ix >= (unsigned)HIN) continue;
        acc += (xp[iy * HIN + ix] - m) * s * wp[ky * 3 + kx];
      }
    }
  }
  y[i] = lrelu(acc);
}

// ---- transposed conv 3x3, stride 2, pad 1, output_pad 1, + bias + LeakyReLU
// weight layout (CIN, COUT, 3, 3) (PyTorch ConvTranspose2d). Gather form:
// out[oy,ox] += x[(oy+1-ky)/2, (ox+1-kx)/2] * w[ci,co,ky,kx] when divisible.
template <int CIN, int HIN, int COUT>
__global__ __launch_bounds__(256) void convt_s2_lrelu(
    const float* __restrict__ x, const float* __restrict__ w,
    const float* __restrict__ bias, const float* __restrict__ nm,
    const float* __restrict__ ns, float* __restrict__ y) {
  constexpr int HOUT = HIN * 2;
  int i = blockIdx.x * 256 + threadIdx.x;
  int ox = i % HOUT;
  int t = i / HOUT;
  int oy = t % HOUT;
  t /= HOUT;
  int co = t % COUT;
  int n = t / COUT;
  float acc = bias[co];
  const float* xn = x + (size_t)n * CIN * HIN * HIN;
  for (int ci = 0; ci < CIN; ++ci) {
    const float* xp = xn + (size_t)ci * HIN * HIN;
    const float* wp = w + ((size_t)ci * COUT + co) * 9;
    const float m = nm ? nm[ci] : 0.f;
    const float s = ns ? ns[ci] : 1.f;
#pragma unroll
    for (int ky = 0; ky < 3; ++ky) {
      const int ty = oy + 1 - ky;
      if (ty < 0 || (ty & 1)) continue;
      const int iy = ty >> 1;
      if (iy >= HIN) continue;
#pragma unroll
      for (int kx = 0; kx < 3; ++kx) {
        const int tx = ox + 1 - kx;
        if (tx < 0 || (tx & 1)) continue;
        const int ix = tx >> 1;
        if (ix >= HIN) continue;
        acc += (xp[iy * HIN + ix] - m) * s * wp[ky * 3 + kx];
      }
    }
  }
  y[i] = lrelu(acc);
}

// ---- final transposed conv 3x3 stride 1 pad 1 + tanh -> 0.5+0.5*t --------
// x: [256,32,64,64] normalized on read; w: (32,3,3,3); out: [256,3,64,64]
__global__ __launch_bounds__(256) void convt4_tanh(
    const float* __restrict__ x, const float* __restrict__ w,
    const float* __restrict__ bias, const float* __restrict__ nm,
    const float* __restrict__ ns, float* __restrict__ out) {
  int i = blockIdx.x * 256 + threadIdx.x;
  int ox = i & 63;
  int t = i >> 6;
  int oy = t & 63;
  t >>= 6;
  int co = t % 3;
  int n = t / 3;
  float acc = bias[co];
  const float* xn = x + (size_t)n * 32 * 4096;
  for (int ci = 0; ci < 32; ++ci) {
    const float* xp = xn + ci * 4096;
    const float* wp = w + (ci * 3 + co) * 9;
    const float m = nm[ci], s = ns[ci];
#pragma unroll
    for (int ky = 0; ky < 3; ++ky) {
      const int iy = oy + 1 - ky;
      if ((unsigned)iy >= 64u) continue;
#pragma unroll
      for (int kx = 0; kx < 3; ++kx) {
        const int ix = ox + 1 - kx;
        if ((unsigned)ix >= 64u) continue;
        acc += (xp[iy * 64 + ix] - m) * s * wp[ky * 3 + kx];
      }
    }
  }
  out[i] = 0.5f + 0.5f * tanhf(acc);
}

// ---- BN stats: one block per (n,c) plane; atomicAdd partials -------------
__global__ __launch_bounds__(256) void bn_stats(const float* __restrict__ x,
                                                float* __restrict__ stats,
                                                int C, int HW) {
  int plane = blockIdx.x;  // n*C + c
  int c = plane % C;
  const float* p = x + (size_t)plane * HW;
  float s = 0.f, q = 0.f;
  for (int j = threadIdx.x; j < HW; j += 256) {
    float v = p[j];
    s += v;
    q += v * v;
  }
  __shared__ float sh[512];
  sh[threadIdx.x] = s;
  sh[256 + threadIdx.x] = q;
  __syncthreads();
  for (int st = 128; st > 0; st >>= 1) {
    if (threadIdx.x < st) {
      sh[threadIdx.x] += sh[threadIdx.x + st];
      sh[256 + threadIdx.x] += sh[256 + threadIdx.x + st];
    }
    __syncthreads();
  }
  if (threadIdx.x == 0) {
    atomicAdd(&stats[c], sh[0]);
    atomicAdd(&stats[256 + c], sh[256]);
  }
}

// ---- BN finalize: stats[c] <- mean, stats[256+c] <- invstd ---------------
__global__ __launch_bounds__(256) void bn_finalize(float* __restrict__ stats,
                                                   int C, float invN) {
  int c = threadIdx.x;
  if (c >= C) return;
  float mean = stats[c] * invN;
  float var = stats[256 + c] * invN - mean * mean;
  stats[c] = mean;
  stats[256 + c] = rsqrtf(var + EPS_BN);
}

// ---- encoder FC: z_e[b, 0:128]=mu, [128:256]=relu(cov) -------------------
// h = a4 [256,256,4,4] flattened [256,4096], normalized per channel c=f>>4.
__global__ __launch_bounds__(256) void fc_enc(
    const float* __restrict__ h, const float* __restrict__ nm,
    const float* __restrict__ ns, const float* __restrict__ wmu,
    const float* __restrict__ bmu, const float* __restrict__ wcov,
    const float* __restrict__ bcov, float* __restrict__ ze) {
  int b = blockIdx.x;   // one batch row per block
  int j = threadIdx.x;  // output feature 0..255
  __shared__ float hn[4096];
  const float* hb = h + (size_t)b * 4096;
  for (int f = threadIdx.x; f < 4096; f += 256) {
    int c = f >> 4;
    hn[f] = (hb[f] - nm[c]) * ns[c];
  }
  __syncthreads();
  bool isCov = j >= 128;
  int jj = isCov ? j - 128 : j;
  const float* wr = (isCov ? wcov : wmu) + (size_t)jj * 4096;
  float acc = (isCov ? bcov : bmu)[jj];
  for (int f = 0; f < 4096; ++f) acc += hn[f] * wr[f];
  if (isCov) acc = fmaxf(acc, 0.f);
  ze[b * 256 + j] = acc;
}

// ---- VQ argmin: one block per b; 8192 codes, 256-dim L2 ------------------
__global__ __launch_bounds__(256) void vq_argmin(const float* __restrict__ ze,
                                                 const float* __restrict__ cb,
                                                 int* __restrict__ idx) {
  int b = blockIdx.x;
  int t = threadIdx.x;
  __shared__ float z[256];
  __shared__ float bval[256];
  __shared__ int bidx[256];
  z[t] = ze[b * 256 + t];
  __syncthreads();
  float best = 3.4e38f;
  int bi = 0x7fffffff;
  for (int k = t; k < 8192; k += 256) {
    const float* ck = cb + (size_t)k * 256;
    float d = 0.f;
    for (int e = 0; e < 256; ++e) {
      float df = z[e] - ck[e];
      d += df * df;
    }
    if (d < best) {  // strict < keeps earliest k within this thread
      best = d;
      bi = k;
    }
  }
  bval[t] = best;
  bidx[t] = bi;
  __syncthreads();
  for (int s = 128; s > 0; s >>= 1) {
    if (t < s) {
      float ov = bval[t + s];
      int oi = bidx[t + s];
      if (ov < bval[t] || (ov == bval[t] && oi < bidx[t])) {
        bval[t] = ov;
        bidx[t] = oi;
      }
    }
    __syncthreads();
  }
  if (t == 0) idx[b] = bidx[0];
}

// ---- gather z_q = cb[idx[b]] and accumulate sum((z_e - z_q)^2) -----------
__global__ __launch_bounds__(256) void vq_gather_loss(
    const float* __restrict__ ze, const float* __restrict__ cb,
    const int* __restrict__ idx, float* __restrict__ zq,
    float* __restrict__ lossacc) {
  int b = blockIdx.x;
  int d = threadIdx.x;
  int i = b * 256 + d;
  float q = cb[(size_t)idx[b] * 256 + d];
  zq[i] = q;
  float df = ze[i] - q;
  float v = df * df;
  __shared__ float sh[256];
  sh[d] = v;
  __syncthreads();
  for (int s = 128; s > 0; s >>= 1) {
    if (d < s) sh[d] += sh[d + s];
    __syncthreads();
  }
  if (d == 0) atomicAdd(lossacc, sh[0]);
}

// ---- decoder FC: g0[b,f] = zq[b,:] . wfc[f,:] + bfc[f] -------------------
__global__ __launch_bounds__(256) void fc_dec(const float* __restrict__ zq,
                                              const float* __restrict__ w,
                                              const float* __restrict__ bias,
                                              float* __restrict__ g0) {
  int i = blockIdx.x * 256 + threadIdx.x;  // 256*4096
  int f = i % 4096;
  int b = i / 4096;
  __shared__ float zs[256];
  zs[threadIdx.x] = zq[b * 256 + threadIdx.x];
  __syncthreads();
  const float* wr = w + (size_t)f * 256;
  float acc = bias[f];
  for (int d = 0; d < 256; ++d) acc += zs[d] * wr[d];
  g0[i] = acc;
}

__global__ void write_loss(const float* __restrict__ lossacc,
                           float* __restrict__ out) {
  out[0] = 2.f * lossacc[0];  // emb_loss + com_loss (equal in forward)
}

// ---------------------------------------------------------------------------
extern "C" void kernel_launch(void* const* d_in, const int* in_sizes, int n_in,
                              void* d_out, int out_size, void* d_ws,
                              size_t ws_size, hipStream_t stream) {
  const float* x = (const float*)d_in[0];
  const float* ew1 = (const float*)d_in[1];
  const float* eb1 = (const float*)d_in[2];
  const float* ew2 = (const float*)d_in[3];
  const float* eb2 = (const float*)d_in[4];
  const float* ew3 = (const float*)d_in[5];
  const float* eb3 = (const float*)d_in[6];
  const float* ew4 = (const float*)d_in[7];
  const float* eb4 = (const float*)d_in[8];
  const float* wmu = (const float*)d_in[9];
  const float* bmu = (const float*)d_in[10];
  const float* wcov = (const float*)d_in[11];
  const float* bcov = (const float*)d_in[12];
  const float* cb = (const float*)d_in[13];
  const float* wfc = (const float*)d_in[14];
  const float* bfc = (const float*)d_in[15];
  const float* wt1 = (const float*)d_in[16];
  const float* bt1 = (const float*)d_in[17];
  const float* wt2 = (const float*)d_in[18];
  const float* bt2 = (const float*)d_in[19];
  const float* wt3 = (const float*)d_in[20];
  const float* bt3 = (const float*)d_in[21];
  const float* wt31 = (const float*)d_in[22];
  const float* bt31 = (const float*)d_in[23];
  const float* wt4 = (const float*)d_in[24];
  const float* bt4 = (const float*)d_in[25];

  float* ws = (float*)d_ws;
  // buffer reuse: encoder buffers are dead by decoder time (same sizes).
  float* a1 = ws;                 // [256,32,32,32]  8388608  (reused as g3)
  float* a2 = a1 + 8388608;       // [256,64,16,16]  4194304  (reused as g2)
  float* a3 = a2 + 4194304;       // [256,128,8,8]   2097152  (reused as g1)
  float* a4 = a3 + 2097152;       // [256,256,4,4]   1048576  (reused as g0)
  float* g31 = a4 + 1048576;      // [256,32,64,64] 33554432
  float* ze = g31 + 33554432;     // [256,256]
  float* zq = ze + 65536;         // [256,256]
  float* stats = zq + 65536;      // 8 layers x 512 floats
  float* lossacc = stats + 4096;  // 1 float
  int* idx = (int*)(lossacc + 4);  // 256 ints
  float* g3 = a1;
  float* g2 = a2;
  float* g1 = a3;
  float* g0 = a4;

  float* st0 = stats + 0 * 512;  // a1  C=32
  float* st1 = stats + 1 * 512;  // a2  C=64
  float* st2 = stats + 2 * 512;  // a3  C=128
  float* st3 = stats + 3 * 512;  // a4  C=256
  float* st4 = stats + 4 * 512;  // g1  C=128
  float* st5 = stats + 5 * 512;  // g2  C=64
  float* st6 = stats + 6 * 512;  // g3  C=32
  float* st7 = stats + 7 * 512;  // g31 C=32

  hipMemsetAsync(stats, 0, (4096 + 8) * sizeof(float), stream);

  // ---- encoder ----
  conv_s2_lrelu<3, 64, 32><<<8388608 / 256, 256, 0, stream>>>(
      x, ew1, eb1, nullptr, nullptr, a1);
  bn_stats<<<256 * 32, 256, 0, stream>>>(a1, st0, 32, 1024);
  bn_finalize<<<1, 256, 0, stream>>>(st0, 32, 1.f / (256.f * 1024.f));

  conv_s2_lrelu<32, 32, 64><<<4194304 / 256, 256, 0, stream>>>(
      a1, ew2, eb2, st0, st0 + 256, a2);
  bn_stats<<<256 * 64, 256, 0, stream>>>(a2, st1, 64, 256);
  bn_finalize<<<1, 256, 0, stream>>>(st1, 64, 1.f / (256.f * 256.f));

  conv_s2_lrelu<64, 16, 128><<<2097152 / 256, 256, 0, stream>>>(
      a2, ew3, eb3, st1, st1 + 256, a3);
  bn_stats<<<256 * 128, 256, 0, stream>>>(a3, st2, 128, 64);
  bn_finalize<<<1, 256, 0, stream>>>(st2, 128, 1.f / (256.f * 64.f));

  conv_s2_lrelu<128, 8, 256><<<1048576 / 256, 256, 0, stream>>>(
      a3, ew4, eb4, st2, st2 + 256, a4);
  bn_stats<<<256 * 256, 256, 0, stream>>>(a4, st3, 256, 16);
  bn_finalize<<<1, 256, 0, stream>>>(st3, 256, 1.f / (256.f * 16.f));

  fc_enc<<<256, 256, 0, stream>>>(a4, st3, st3 + 256, wmu, bmu, wcov, bcov, ze);

  // ---- VQ ----
  vq_argmin<<<256, 256, 0, stream>>>(ze, cb, idx);
  vq_gather_loss<<<256, 256, 0, stream>>>(ze, cb, idx, zq, lossacc);

  // ---- decoder ----
  fc_dec<<<4096, 256, 0, stream>>>(zq, wfc, bfc, g0);

  convt_s2_lrelu<256, 4, 128><<<2097152 / 256, 256, 0, stream>>>(
      g0, wt1, bt1, nullptr, nullptr, g1);
  bn_stats<<<256 * 128, 256, 0, stream>>>(g1, st4, 128, 64);
  bn_finalize<<<1, 256, 0, stream>>>(st4, 128, 1.f / (256.f * 64.f));

  convt_s2_lrelu<128, 8, 64><<<4194304 / 256, 256, 0, stream>>>(
      g1, wt2, bt2, st4, st4 + 256, g2);
  bn_stats<<<256 * 64, 256, 0, stream>>>(g2, st5, 64, 256);
  bn_finalize<<<1, 256, 0, stream>>>(st5, 64, 1.f / (256.f * 256.f));

  convt_s2_lrelu<64, 16, 32><<<8388608 / 256, 256, 0, stream>>>(
      g2, wt3, bt3, st5, st5 + 256, g3);
  bn_stats<<<256 * 32, 256, 0, stream>>>(g3, st6, 32, 1024);
  bn_finalize<<<1, 256, 0, stream>>>(st6, 32, 1.f / (256.f * 1024.f));

  convt_s2_lrelu<32, 32, 32><<<33554432 / 256, 256, 0, stream>>>(
      g3, wt31, bt31, st6, st6 + 256, g31);
  bn_stats<<<256 * 32, 256, 0, stream>>>(g31, st7, 32, 4096);
  bn_finalize<<<1, 256, 0, stream>>>(st7, 32, 1.f / (256.f * 4096.f));

  convt4_tanh<<<3145728 / 256, 256, 0, stream>>>(g31, wt4, bt4, st7, st7 + 256,
                                                 (float*)d_out);

  write_loss<<<1, 1, 0, stream>>>(lossacc, (float*)d_out + 3145728);
}

// Round 2
// 2048.390 us; speedup vs baseline: 5.1911x; 5.1911x over previous
//
#include <hip/hip_runtime.h>
#include <cmath>

// ---------------------------------------------------------------------------
// VQ-VAE forward, fp32. B=256, C=3, HW=64, D=256, K=8192, LAT=128
// R1: ILP-tiled convs (4co x 2px), parity-specialized convT (4co x 2 quads),
// BN stats fused into conv epilogues, GEMM-tiled FC + VQ distance.
// ---------------------------------------------------------------------------

#define EPS_BN 1e-5f
#define Bsz 256

__device__ __forceinline__ float lrelu(float v) { return v >= 0.f ? v : 0.01f * v; }

// ---- stride-2 conv 3x3 pad1 + bias + LeakyReLU + fused BN-stat atomics ----
// thread: 4 output channels x 2 horizontally-adjacent output pixels.
// grid: (B*HOUT*HOUT/2/256, COUT/4). weights (COUT,CIN,3,3).
template <int CIN, int HIN, int COUT>
__global__ __launch_bounds__(256) void conv_s2(
    const float* __restrict__ x, const float* __restrict__ w,
    const float* __restrict__ bias, const float* __restrict__ nm,
    const float* __restrict__ ns, float* __restrict__ y,
    float* __restrict__ st) {
  constexpr int HOUT = HIN / 2;
  constexpr int PX2 = HOUT * HOUT / 2;
  const int idx = blockIdx.x * 256 + threadIdx.x;
  const int p = idx % PX2;
  const int n = idx / PX2;
  const int oy = p / (HOUT / 2);
  const int ox0 = (p % (HOUT / 2)) * 2;
  const int cog = blockIdx.y * 4;

  float acc[4][2];
#pragma unroll
  for (int j = 0; j < 4; ++j) acc[j][0] = acc[j][1] = bias[cog + j];

  const float* xn = x + (size_t)n * CIN * HIN * HIN;
  const int iy0 = oy * 2 - 1, ix0 = ox0 * 2 - 1;
  const bool hasN = (nm != nullptr);

  for (int ci = 0; ci < CIN; ++ci) {
    const float* xp = xn + (size_t)ci * HIN * HIN;
    const float m = hasN ? nm[ci] : 0.f;
    const float s = hasN ? ns[ci] : 1.f;
    float v[3][5];
#pragma unroll
    for (int ky = 0; ky < 3; ++ky) {
      const int iy = iy0 + ky;
      const bool oky = (unsigned)iy < (unsigned)HIN;
#pragma unroll
      for (int c = 0; c < 5; ++c) {
        const int ix = ix0 + c;
        const bool ok = oky && ((unsigned)ix < (unsigned)HIN);
        v[ky][c] = ok ? (xp[iy * HIN + ix] - m) * s : 0.f;
      }
    }
#pragma unroll
    for (int j = 0; j < 4; ++j) {
      const float* wp = w + ((size_t)(cog + j) * CIN + ci) * 9;
      float w9[9];
#pragma unroll
      for (int t = 0; t < 9; ++t) w9[t] = wp[t];
#pragma unroll
      for (int ky = 0; ky < 3; ++ky)
#pragma unroll
        for (int kx = 0; kx < 3; ++kx) {
          acc[j][0] = fmaf(v[ky][kx], w9[ky * 3 + kx], acc[j][0]);
          acc[j][1] = fmaf(v[ky][kx + 2], w9[ky * 3 + kx], acc[j][1]);
        }
    }
  }

  __shared__ float red[2][4][4];
  const int wv = threadIdx.x >> 6, ln = threadIdx.x & 63;
#pragma unroll
  for (int j = 0; j < 4; ++j) {
    const float o0 = lrelu(acc[j][0]), o1 = lrelu(acc[j][1]);
    float2 o2 = make_float2(o0, o1);
    *(float2*)&y[((size_t)n * COUT + cog + j) * (HOUT * HOUT) + oy * HOUT + ox0] = o2;
    float s_ = o0 + o1, q_ = o0 * o0 + o1 * o1;
#pragma unroll
    for (int off = 32; off > 0; off >>= 1) {
      s_ += __shfl_down(s_, off);
      q_ += __shfl_down(q_, off);
    }
    if (ln == 0) { red[0][wv][j] = s_; red[1][wv][j] = q_; }
  }
  __syncthreads();
  if (threadIdx.x < 4) {
    const int j = threadIdx.x;
    float S = red[0][0][j] + red[0][1][j] + red[0][2][j] + red[0][3][j];
    float Q = red[1][0][j] + red[1][1][j] + red[1][2][j] + red[1][3][j];
    atomicAdd(&st[cog + j], S);
    atomicAdd(&st[256 + cog + j], Q);
  }
}

// ---- stride-2 transposed conv 3x3 pad1 outpad1 + bias + LeakyReLU + stats -
// thread: 4 output channels x 2 adjacent 2x2 output quads (2x4 output tile).
// grid: (B*HIN*HIN/2/256, COUT/4). weights (CIN,COUT,3,3).
template <int CIN, int HIN, int COUT>
__global__ __launch_bounds__(256) void convt_s2(
    const float* __restrict__ x, const float* __restrict__ w,
    const float* __restrict__ bias, const float* __restrict__ nm,
    const float* __restrict__ ns, float* __restrict__ y,
    float* __restrict__ st) {
  constexpr int HOUT = 2 * HIN;
  constexpr int QP2 = HIN * (HIN / 2);
  const int idx = blockIdx.x * 256 + threadIdx.x;
  const int p = idx % QP2;
  const int n = idx / QP2;
  const int y0 = p / (HIN / 2);
  const int x0 = (p % (HIN / 2)) * 2;
  const int cog = blockIdx.y * 4;

  float acc[4][8];
#pragma unroll
  for (int j = 0; j < 4; ++j)
#pragma unroll
    for (int q = 0; q < 8; ++q) acc[j][q] = bias[cog + j];

  const float* xn = x + (size_t)n * CIN * HIN * HIN;
  const bool hasN = (nm != nullptr);
  const bool oky = (y0 + 1) < HIN;
  const bool okx = (x0 + 2) < HIN;

  for (int ci = 0; ci < CIN; ++ci) {
    const float* xp = xn + (size_t)ci * HIN * HIN;
    const float m = hasN ? nm[ci] : 0.f;
    const float s = hasN ? ns[ci] : 1.f;
    const float v00 = (xp[y0 * HIN + x0] - m) * s;
    const float v01 = (xp[y0 * HIN + x0 + 1] - m) * s;
    const float v02 = okx ? (xp[y0 * HIN + x0 + 2] - m) * s : 0.f;
    const float v10 = oky ? (xp[(y0 + 1) * HIN + x0] - m) * s : 0.f;
    const float v11 = oky ? (xp[(y0 + 1) * HIN + x0 + 1] - m) * s : 0.f;
    const float v12 = (oky && okx) ? (xp[(y0 + 1) * HIN + x0 + 2] - m) * s : 0.f;
#pragma unroll
    for (int j = 0; j < 4; ++j) {
      const float* wp = w + ((size_t)ci * COUT + cog + j) * 9;
      float w9[9];
#pragma unroll
      for (int t = 0; t < 9; ++t) w9[t] = wp[t];
      // quad A: output cols 2x0, 2x0+1 ; quad B: cols 2x0+2, 2x0+3
      acc[j][0] = fmaf(v00, w9[4], acc[j][0]);
      acc[j][1] = fmaf(v00, w9[5], fmaf(v01, w9[3], acc[j][1]));
      acc[j][4] = fmaf(v00, w9[7], fmaf(v10, w9[1], acc[j][4]));
      acc[j][5] = fmaf(v00, w9[8], fmaf(v01, w9[6],
                  fmaf(v10, w9[2], fmaf(v11, w9[0], acc[j][5]))));
      acc[j][2] = fmaf(v01, w9[4], acc[j][2]);
      acc[j][3] = fmaf(v01, w9[5], fmaf(v02, w9[3], acc[j][3]));
      acc[j][6] = fmaf(v01, w9[7], fmaf(v11, w9[1], acc[j][6]));
      acc[j][7] = fmaf(v01, w9[8], fmaf(v02, w9[6],
                  fmaf(v11, w9[2], fmaf(v12, w9[0], acc[j][7]))));
    }
  }

  __shared__ float red[2][4][4];
  const int wv = threadIdx.x >> 6, ln = threadIdx.x & 63;
#pragma unroll
  for (int j = 0; j < 4; ++j) {
    float o[8];
#pragma unroll
    for (int q = 0; q < 8; ++q) o[q] = lrelu(acc[j][q]);
    float* yp = &y[((size_t)n * COUT + cog + j) * (HOUT * HOUT) + (2 * y0) * HOUT + 2 * x0];
    *(float4*)yp = make_float4(o[0], o[1], o[2], o[3]);
    *(float4*)(yp + HOUT) = make_float4(o[4], o[5], o[6], o[7]);
    float s_ = 0.f, q_ = 0.f;
#pragma unroll
    for (int q = 0; q < 8; ++q) { s_ += o[q]; q_ += o[q] * o[q]; }
#pragma unroll
    for (int off = 32; off > 0; off >>= 1) {
      s_ += __shfl_down(s_, off);
      q_ += __shfl_down(q_, off);
    }
    if (ln == 0) { red[0][wv][j] = s_; red[1][wv][j] = q_; }
  }
  __syncthreads();
  if (threadIdx.x < 4) {
    const int j = threadIdx.x;
    float S = red[0][0][j] + red[0][1][j] + red[0][2][j] + red[0][3][j];
    float Q = red[1][0][j] + red[1][1][j] + red[1][2][j] + red[1][3][j];
    atomicAdd(&st[cog + j], S);
    atomicAdd(&st[256 + cog + j], Q);
  }
}

// ---- final convT 3x3 stride1 pad1 + sigmoid(2a) (== 0.5+0.5*tanh(a)) ------
// thread: 3 channels x 2x2 pixel tile. grid: B*1024/256 blocks.
__global__ __launch_bounds__(256) void convt4_tanh(
    const float* __restrict__ x, const float* __restrict__ w,
    const float* __restrict__ bias, const float* __restrict__ nm,
    const float* __restrict__ ns, float* __restrict__ out) {
  const int idx = blockIdx.x * 256 + threadIdx.x;
  const int p = idx & 1023;
  const int n = idx >> 10;
  const int y0 = (p >> 5) * 2;
  const int x0 = (p & 31) * 2;

  float acc[3][4];
#pragma unroll
  for (int co = 0; co < 3; ++co)
#pragma unroll
    for (int q = 0; q < 4; ++q) acc[co][q] = bias[co];

  const float* xn = x + (size_t)n * 32 * 4096;
  for (int ci = 0; ci < 32; ++ci) {
    const float* xp = xn + ci * 4096;
    const float m = nm[ci], s = ns[ci];
    float v[4][4];
#pragma unroll
    for (int r = 0; r < 4; ++r) {
      const int iy = y0 - 1 + r;
      const bool oky = (unsigned)iy < 64u;
#pragma unroll
      for (int c = 0; c < 4; ++c) {
        const int ix = x0 - 1 + c;
        const bool ok = oky && ((unsigned)ix < 64u);
        v[r][c] = ok ? (xp[iy * 64 + ix] - m) * s : 0.f;
      }
    }
#pragma unroll
    for (int co = 0; co < 3; ++co) {
      const float* wp = w + ((size_t)ci * 3 + co) * 9;
      float w9[9];
#pragma unroll
      for (int t = 0; t < 9; ++t) w9[t] = wp[t];
#pragma unroll
      for (int dy = 0; dy < 2; ++dy)
#pragma unroll
        for (int dx = 0; dx < 2; ++dx)
#pragma unroll
          for (int ky = 0; ky < 3; ++ky)
#pragma unroll
            for (int kx = 0; kx < 3; ++kx)
              acc[co][dy * 2 + dx] = fmaf(v[dy + 2 - ky][dx + 2 - kx],
                                          w9[ky * 3 + kx], acc[co][dy * 2 + dx]);
    }
  }
#pragma unroll
  for (int co = 0; co < 3; ++co) {
    float o[4];
#pragma unroll
    for (int q = 0; q < 4; ++q) o[q] = 1.f / (1.f + __expf(-2.f * acc[co][q]));
    float* op = &out[(((size_t)n * 3 + co) << 12) + y0 * 64 + x0];
    *(float2*)op = make_float2(o[0], o[1]);
    *(float2*)(op + 64) = make_float2(o[2], o[3]);
  }
}

// ---- BN finalize: stats[c] <- mean, stats[256+c] <- invstd ---------------
__global__ __launch_bounds__(256) void bn_finalize(float* __restrict__ stats,
                                                   int C, float invN) {
  int c = threadIdx.x;
  if (c >= C) return;
  float mean = stats[c] * invN;
  float var = stats[256 + c] * invN - mean * mean;
  stats[c] = mean;
  stats[256 + c] = rsqrtf(var + EPS_BN);
}

// ---- tiled GEMM: C[M,N] = alpha * A[M,K] * B[N,K]^T (+bias, act) ---------
// 64x64 tile, BK=16, 256 threads, 4x4 micro-tile. Optional per-channel norm
// on A (channel = k>>4). gridDim.z>1 => write raw partials to P instead.
__global__ __launch_bounds__(256) void gemm_abt(
    const float* __restrict__ A, const float* __restrict__ B,
    const float* __restrict__ bias, const float* __restrict__ nmA,
    const float* __restrict__ nsA, float* __restrict__ C,
    float* __restrict__ P, int K, int ldc, int col0, float alpha, int act) {
  __shared__ float As[16][68];
  __shared__ float Bsh[16][68];
  const int tid = threadIdx.x;
  const int lm = tid >> 2, lk = (tid & 3) << 2;
  const int KS = gridDim.z;
  const int kChunk = K / KS;
  const int kStart = blockIdx.z * kChunk;
  const float* Arow = A + (size_t)(blockIdx.y * 64 + lm) * K + lk;
  const float* Brow = B + (size_t)(blockIdx.x * 64 + lm) * K + lk;
  float acc[4][4] = {};
  const int m0 = (tid >> 4) << 2, n0 = (tid & 15) << 2;

  for (int k0 = kStart; k0 < kStart + kChunk; k0 += 16) {
    float4 av = *(const float4*)(Arow + k0);
    float4 bv = *(const float4*)(Brow + k0);
    if (nmA) {
      const int ch = (k0 + lk) >> 4;
      const float m = nmA[ch], s = nsA[ch];
      av.x = (av.x - m) * s; av.y = (av.y - m) * s;
      av.z = (av.z - m) * s; av.w = (av.w - m) * s;
    }
    As[lk + 0][lm] = av.x; As[lk + 1][lm] = av.y;
    As[lk + 2][lm] = av.z; As[lk + 3][lm] = av.w;
    Bsh[lk + 0][lm] = bv.x; Bsh[lk + 1][lm] = bv.y;
    Bsh[lk + 2][lm] = bv.z; Bsh[lk + 3][lm] = bv.w;
    __syncthreads();
#pragma unroll
    for (int kk = 0; kk < 16; ++kk) {
      const float4 a = *(const float4*)&As[kk][m0];
      const float4 b = *(const float4*)&Bsh[kk][n0];
      acc[0][0] = fmaf(a.x, b.x, acc[0][0]); acc[0][1] = fmaf(a.x, b.y, acc[0][1]);
      acc[0][2] = fmaf(a.x, b.z, acc[0][2]); acc[0][3] = fmaf(a.x, b.w, acc[0][3]);
      acc[1][0] = fmaf(a.y, b.x, acc[1][0]); acc[1][1] = fmaf(a.y, b.y, acc[1][1]);
      acc[1][2] = fmaf(a.y, b.z, acc[1][2]); acc[1][3] = fmaf(a.y, b.w, acc[1][3]);
      acc[2][0] = fmaf(a.z, b.x, acc[2][0]); acc[2][1] = fmaf(a.z, b.y, acc[2][1]);
      acc[2][2] = fmaf(a.z, b.z, acc[2][2]); acc[2][3] = fmaf(a.z, b.w, acc[2][3]);
      acc[3][0] = fmaf(a.w, b.x, acc[3][0]); acc[3][1] = fmaf(a.w, b.y, acc[3][1]);
      acc[3][2] = fmaf(a.w, b.z, acc[3][2]); acc[3][3] = fmaf(a.w, b.w, acc[3][3]);
    }
    __syncthreads();
  }

  const int gm = blockIdx.y * 64 + m0;
  const int gn = blockIdx.x * 64 + n0;
  if (KS == 1) {
#pragma unroll
    for (int i = 0; i < 4; ++i) {
      float4 o;
      o.x = alpha * acc[i][0] + bias[gn + 0];
      o.y = alpha * acc[i][1] + bias[gn + 1];
      o.z = alpha * acc[i][2] + bias[gn + 2];
      o.w = alpha * acc[i][3] + bias[gn + 3];
      if (act == 1) {
        o.x = fmaxf(o.x, 0.f); o.y = fmaxf(o.y, 0.f);
        o.z = fmaxf(o.z, 0.f); o.w = fmaxf(o.w, 0.f);
      }
      *(float4*)&C[(size_t)(gm + i) * ldc + col0 + gn] = o;
    }
  } else {
    const int M = gridDim.y * 64, N = gridDim.x * 64;
#pragma unroll
    for (int i = 0; i < 4; ++i)
      *(float4*)&P[((size_t)blockIdx.z * M + gm + i) * N + gn] =
          make_float4(acc[i][0], acc[i][1], acc[i][2], acc[i][3]);
  }
}

// ---- reduce k-split partials: C = act(alpha * sum_z P + bias) ------------
__global__ __launch_bounds__(256) void gemm_reduce(
    const float* __restrict__ P, float* __restrict__ C,
    const float* __restrict__ bias, int M, int N, int ldc, int col0,
    float alpha, int act, int KS) {
  const int idx = blockIdx.x * 256 + threadIdx.x;
  if (idx >= M * N) return;
  const int m = idx / N, n = idx % N;
  float s = 0.f;
  for (int z = 0; z < KS; ++z) s += P[((size_t)z * M + m) * N + n];
  float v = alpha * s + bias[n];
  if (act == 1) v = fmaxf(v, 0.f);
  C[(size_t)m * ldc + col0 + n] = v;
}

// ---- per-row squared norm of codebook: csq[k] = ||cb[k]||^2 --------------
__global__ __launch_bounds__(256) void rowsq(const float* __restrict__ cb,
                                             float* __restrict__ csq) {
  const int row = blockIdx.x * 4 + (threadIdx.x >> 6);
  const int ln = threadIdx.x & 63;
  const float4 v = ((const float4*)(cb + (size_t)row * 256))[ln];
  float s = v.x * v.x + v.y * v.y + v.z * v.z + v.w * v.w;
#pragma unroll
  for (int off = 32; off > 0; off >>= 1) s += __shfl_down(s, off);
  if (ln == 0) csq[row] = s;
}

// ---- argmin over d2 rows (first-min tie-break like jnp.argmin) -----------
__global__ __launch_bounds__(256) void argmin_d2(const float* __restrict__ d2,
                                                 int* __restrict__ idx) {
  const int b = blockIdx.x, t = threadIdx.x;
  const float* row = d2 + (size_t)b * 8192;
  float best = 3.4e38f;
  int bi = 0x7fffffff;
  for (int k = t; k < 8192; k += 256) {
    const float v = row[k];
    if (v < best) { best = v; bi = k; }
  }
  __shared__ float bval[256];
  __shared__ int bidx[256];
  bval[t] = best; bidx[t] = bi;
  __syncthreads();
  for (int s = 128; s > 0; s >>= 1) {
    if (t < s) {
      const float ov = bval[t + s];
      const int oi = bidx[t + s];
      if (ov < bval[t] || (ov == bval[t] && oi < bidx[t])) {
        bval[t] = ov; bidx[t] = oi;
      }
    }
    __syncthreads();
  }
  if (t == 0) idx[b] = bidx[0];
}

// ---- gather z_q = cb[idx[b]] and accumulate sum((z_e - z_q)^2) -----------
__global__ __launch_bounds__(256) void vq_gather_loss(
    const float* __restrict__ ze, const float* __restrict__ cb,
    const int* __restrict__ idx, float* __restrict__ zq,
    float* __restrict__ lossacc) {
  const int b = blockIdx.x, d = threadIdx.x;
  const int i = b * 256 + d;
  const float q = cb[(size_t)idx[b] * 256 + d];
  zq[i] = q;
  const float df = ze[i] - q;
  float v = df * df;
  __shared__ float sh[256];
  sh[d] = v;
  __syncthreads();
  for (int s = 128; s > 0; s >>= 1) {
    if (d < s) sh[d] += sh[d + s];
    __syncthreads();
  }
  if (d == 0) atomicAdd(lossacc, sh[0]);
}

__global__ void write_loss(const float* __restrict__ lossacc,
                           float* __restrict__ out) {
  out[0] = 2.f * lossacc[0];
}

// ---------------------------------------------------------------------------
extern "C" void kernel_launch(void* const* d_in, const int* in_sizes, int n_in,
                              void* d_out, int out_size, void* d_ws,
                              size_t ws_size, hipStream_t stream) {
  const float* x = (const float*)d_in[0];
  const float* ew1 = (const float*)d_in[1];
  const float* eb1 = (const float*)d_in[2];
  const float* ew2 = (const float*)d_in[3];
  const float* eb2 = (const float*)d_in[4];
  const float* ew3 = (const float*)d_in[5];
  const float* eb3 = (const float*)d_in[6];
  const float* ew4 = (const float*)d_in[7];
  const float* eb4 = (const float*)d_in[8];
  const float* wmu = (const float*)d_in[9];
  const float* bmu = (const float*)d_in[10];
  const float* wcov = (const float*)d_in[11];
  const float* bcov = (const float*)d_in[12];
  const float* cb = (const float*)d_in[13];
  const float* wfc = (const float*)d_in[14];
  const float* bfc = (const float*)d_in[15];
  const float* wt1 = (const float*)d_in[16];
  const float* bt1 = (const float*)d_in[17];
  const float* wt2 = (const float*)d_in[18];
  const float* bt2 = (const float*)d_in[19];
  const float* wt3 = (const float*)d_in[20];
  const float* bt3 = (const float*)d_in[21];
  const float* wt31 = (const float*)d_in[22];
  const float* bt31 = (const float*)d_in[23];
  const float* wt4 = (const float*)d_in[24];
  const float* bt4 = (const float*)d_in[25];

  float* ws = (float*)d_ws;
  float* a1 = ws;              // [256,32,32,32]  8388608  (reused as g3)
  float* a2 = a1 + 8388608;    // [256,64,16,16]  4194304  (reused as g2)
  float* a3 = a2 + 4194304;    // [256,128,8,8]   2097152  (reused as g1)
  float* a4 = a3 + 2097152;    // [256,256,4,4]   1048576  (reused as g0)
  float* g31 = a4 + 1048576;   // [256,32,64,64] 33554432
  // d2 / P / csq alias g31's space (all dead before convt1 writes g1..g31)
  float* d2 = g31;             // [256,8192] 2097152
  float* P = g31 + 2097152;    // k-split partials, 8*256*128 = 262144
  float* csq = g31 + 2359296;  // 8192
  float* ze = g31 + 33554432;  // [256,256]
  float* zq = ze + 65536;
  float* stats = zq + 65536;   // 8 layers x 512
  float* lossacc = stats + 4096;
  int* idx = (int*)(lossacc + 4);
  float* g3 = a1;
  float* g2 = a2;
  float* g1 = a3;
  float* g0 = a4;

  float* st0 = stats + 0 * 512;
  float* st1 = stats + 1 * 512;
  float* st2 = stats + 2 * 512;
  float* st3 = stats + 3 * 512;
  float* st4 = stats + 4 * 512;
  float* st5 = stats + 5 * 512;
  float* st6 = stats + 6 * 512;
  float* st7 = stats + 7 * 512;

  hipMemsetAsync(stats, 0, (4096 + 8) * sizeof(float), stream);

  // ---- encoder ----
  conv_s2<3, 64, 32><<<dim3(512, 8), 256, 0, stream>>>(x, ew1, eb1, nullptr, nullptr, a1, st0);
  bn_finalize<<<1, 256, 0, stream>>>(st0, 32, 1.f / (256.f * 1024.f));
  conv_s2<32, 32, 64><<<dim3(128, 16), 256, 0, stream>>>(a1, ew2, eb2, st0, st0 + 256, a2, st1);
  bn_finalize<<<1, 256, 0, stream>>>(st1, 64, 1.f / (256.f * 256.f));
  conv_s2<64, 16, 128><<<dim3(32, 32), 256, 0, stream>>>(a2, ew3, eb3, st1, st1 + 256, a3, st2);
  bn_finalize<<<1, 256, 0, stream>>>(st2, 128, 1.f / (256.f * 64.f));
  conv_s2<128, 8, 256><<<dim3(8, 64), 256, 0, stream>>>(a3, ew4, eb4, st2, st2 + 256, a4, st3);
  bn_finalize<<<1, 256, 0, stream>>>(st3, 256, 1.f / (256.f * 16.f));

  // ---- encoder FC (k-split GEMM, deterministic reduce) ----
  gemm_abt<<<dim3(2, 4, 8), 256, 0, stream>>>(a4, wmu, nullptr, st3, st3 + 256,
                                              nullptr, P, 4096, 0, 0, 1.f, 0);
  gemm_reduce<<<128, 256, 0, stream>>>(P, ze, bmu, 256, 128, 256, 0, 1.f, 0, 8);
  gemm_abt<<<dim3(2, 4, 8), 256, 0, stream>>>(a4, wcov, nullptr, st3, st3 + 256,
                                              nullptr, P, 4096, 0, 0, 1.f, 0);
  gemm_reduce<<<128, 256, 0, stream>>>(P, ze, bcov, 256, 128, 256, 128, 1.f, 1, 8);

  // ---- VQ: d2[b,k] = ||c_k||^2 - 2 z.c (row-constant ||z||^2 dropped) ----
  rowsq<<<2048, 256, 0, stream>>>(cb, csq);
  gemm_abt<<<dim3(128, 4, 1), 256, 0, stream>>>(ze, cb, csq, nullptr, nullptr,
                                                d2, nullptr, 256, 8192, 0, -2.f, 0);
  argmin_d2<<<256, 256, 0, stream>>>(d2, idx);
  vq_gather_loss<<<256, 256, 0, stream>>>(ze, cb, idx, zq, lossacc);

  // ---- decoder FC ----
  gemm_abt<<<dim3(64, 4, 1), 256, 0, stream>>>(zq, wfc, bfc, nullptr, nullptr,
                                               g0, nullptr, 256, 4096, 0, 1.f, 0);

  // ---- decoder ----
  convt_s2<256, 4, 128><<<dim3(8, 32), 256, 0, stream>>>(g0, wt1, bt1, nullptr, nullptr, g1, st4);
  bn_finalize<<<1, 256, 0, stream>>>(st4, 128, 1.f / (256.f * 64.f));
  convt_s2<128, 8, 64><<<dim3(32, 16), 256, 0, stream>>>(g1, wt2, bt2, st4, st4 + 256, g2, st5);
  bn_finalize<<<1, 256, 0, stream>>>(st5, 64, 1.f / (256.f * 256.f));
  convt_s2<64, 16, 32><<<dim3(128, 8), 256, 0, stream>>>(g2, wt3, bt3, st5, st5 + 256, g3, st6);
  bn_finalize<<<1, 256, 0, stream>>>(st6, 32, 1.f / (256.f * 1024.f));
  convt_s2<32, 32, 32><<<dim3(512, 8), 256, 0, stream>>>(g3, wt31, bt31, st6, st6 + 256, g31, st7);
  bn_finalize<<<1, 256, 0, stream>>>(st7, 32, 1.f / (256.f * 4096.f));

  convt4_tanh<<<1024, 256, 0, stream>>>(g31, wt4, bt4, st7, st7 + 256, (float*)d_out);
  write_loss<<<1, 1, 0, stream>>>(lossacc, (float*)d_out + 3145728);
}

// Round 3
// 1984.170 us; speedup vs baseline: 5.3591x; 1.0324x over previous
//
#include <hip/hip_runtime.h>
#include <cmath>

// ---------------------------------------------------------------------------
// VQ-VAE forward, fp32. B=256, C=3, HW=64, D=256, K=8192, LAT=128
// R2: LDS-staged weights (broadcast reads), software-pipelined input loads,
// BN finalize folded into consumers (no bn_finalize launches), 4co x 2x2px
// conv tiles, CO=2 variants for deep layers to keep >=2 blocks/CU.
// ---------------------------------------------------------------------------

#define EPS_BN 1e-5f

__device__ __forceinline__ float lrelu(float v) { return v >= 0.f ? v : 0.01f * v; }

// ---- stride-2 conv 3x3 pad1 + bias + LeakyReLU + fused BN-stat atomics ----
// thread: CO output channels x 2x2 output quad. grid: (B*(HOUT/2)^2/256, COUT/CO)
// weights (COUT,CIN,3,3) staged in LDS. Input normalized on read from raw st.
template <int CIN, int HIN, int COUT, int CO, bool HASN>
__global__ __launch_bounds__(256) void conv_s2(
    const float* __restrict__ x, const float* __restrict__ w,
    const float* __restrict__ bias, const float* __restrict__ st, float invN,
    float* __restrict__ y, float* __restrict__ stOut) {
  constexpr int HOUT = HIN / 2;
  constexpr int Q = HOUT / 2;
  const int tid = threadIdx.x;
  const int cog = blockIdx.y * CO;

  __shared__ float lw[CO * CIN * 12];
  __shared__ float nrm[2][HASN ? CIN : 1];
  __shared__ float red[2][4][4];

  for (int i = tid; i < CO * CIN * 9; i += 256) {
    int cor = i / (CIN * 9);
    int rem = i - cor * (CIN * 9);
    int ci = rem / 9, k = rem - ci * 9;
    lw[(cor * CIN + ci) * 12 + k] = w[(size_t)cog * CIN * 9 + i];
  }
  if (HASN) {
    for (int c = tid; c < CIN; c += 256) {
      float m = st[c] * invN;
      float var = st[256 + c] * invN - m * m;
      float s = rsqrtf(var + EPS_BN);
      nrm[0][c] = s;
      nrm[1][c] = m * s;
    }
  }
  __syncthreads();

  const int idx = blockIdx.x * 256 + tid;
  const int q = idx % (Q * Q);
  const int n = idx / (Q * Q);
  const int qy = q / Q, qx = q % Q;
  const int iy0 = 4 * qy - 1, ix0 = 4 * qx - 1;
  const float* xn = x + (size_t)n * CIN * HIN * HIN;

  bool okr[5], okc[5];
#pragma unroll
  for (int r = 0; r < 5; ++r) okr[r] = (unsigned)(iy0 + r) < (unsigned)HIN;
#pragma unroll
  for (int c = 0; c < 5; ++c) okc[c] = (unsigned)(ix0 + c) < (unsigned)HIN;

  float acc[CO][4];
#pragma unroll
  for (int j = 0; j < CO; ++j) {
    const float b = bias[cog + j];
#pragma unroll
    for (int p = 0; p < 4; ++p) acc[j][p] = b;
  }

  float v[5][5];
  {
    const float* xp = xn;
    const float s = HASN ? nrm[0][0] : 1.f;
    const float ms = HASN ? nrm[1][0] : 0.f;
#pragma unroll
    for (int r = 0; r < 5; ++r)
#pragma unroll
      for (int c = 0; c < 5; ++c)
        v[r][c] = (okr[r] && okc[c])
                      ? fmaf(xp[(iy0 + r) * HIN + ix0 + c], s, -ms) : 0.f;
  }

  for (int ci = 0; ci < CIN; ++ci) {
    float vn[5][5];
    if (ci + 1 < CIN) {
      const float* xp = xn + (size_t)(ci + 1) * HIN * HIN;
      const float s = HASN ? nrm[0][ci + 1] : 1.f;
      const float ms = HASN ? nrm[1][ci + 1] : 0.f;
#pragma unroll
      for (int r = 0; r < 5; ++r)
#pragma unroll
        for (int c = 0; c < 5; ++c)
          vn[r][c] = (okr[r] && okc[c])
                         ? fmaf(xp[(iy0 + r) * HIN + ix0 + c], s, -ms) : 0.f;
    }
#pragma unroll
    for (int j = 0; j < CO; ++j) {
      const float* wj = &lw[(j * CIN + ci) * 12];
      const float4 wa = *(const float4*)wj;
      const float4 wb = *(const float4*)(wj + 4);
      const float w8 = wj[8];
      const float w9[9] = {wa.x, wa.y, wa.z, wa.w, wb.x, wb.y, wb.z, wb.w, w8};
#pragma unroll
      for (int dy = 0; dy < 2; ++dy)
#pragma unroll
        for (int dx = 0; dx < 2; ++dx)
#pragma unroll
          for (int ky = 0; ky < 3; ++ky)
#pragma unroll
            for (int kx = 0; kx < 3; ++kx)
              acc[j][dy * 2 + dx] = fmaf(v[2 * dy + ky][2 * dx + kx],
                                         w9[ky * 3 + kx], acc[j][dy * 2 + dx]);
    }
    if (ci + 1 < CIN) {
#pragma unroll
      for (int r = 0; r < 5; ++r)
#pragma unroll
        for (int c = 0; c < 5; ++c) v[r][c] = vn[r][c];
    }
  }

  const int wv = tid >> 6, ln = tid & 63;
#pragma unroll
  for (int j = 0; j < CO; ++j) {
    float o[4];
#pragma unroll
    for (int p = 0; p < 4; ++p) o[p] = lrelu(acc[j][p]);
    float* yp = &y[((size_t)n * COUT + cog + j) * (HOUT * HOUT) +
                   (2 * qy) * HOUT + 2 * qx];
    *(float2*)yp = make_float2(o[0], o[1]);
    *(float2*)(yp + HOUT) = make_float2(o[2], o[3]);
    float s_ = o[0] + o[1] + o[2] + o[3];
    float q_ = o[0] * o[0] + o[1] * o[1] + o[2] * o[2] + o[3] * o[3];
#pragma unroll
    for (int off = 32; off > 0; off >>= 1) {
      s_ += __shfl_down(s_, off);
      q_ += __shfl_down(q_, off);
    }
    if (ln == 0) { red[0][wv][j] = s_; red[1][wv][j] = q_; }
  }
  __syncthreads();
  if (tid < CO) {
    float S = red[0][0][tid] + red[0][1][tid] + red[0][2][tid] + red[0][3][tid];
    float Qq = red[1][0][tid] + red[1][1][tid] + red[1][2][tid] + red[1][3][tid];
    atomicAdd(&stOut[cog + tid], S);
    atomicAdd(&stOut[256 + cog + tid], Qq);
  }
}

// ---- stride-2 transposed conv 3x3 pad1 outpad1 + bias + LeakyReLU + stats -
// thread: CO output channels x 2 adjacent 2x2 quads (2x4 outputs).
// grid: (B*HIN*HIN/2/256, COUT/CO). weights (CIN,COUT,3,3) staged in LDS.
template <int CIN, int HIN, int COUT, int CO, bool HASN>
__global__ __launch_bounds__(256) void convt_s2(
    const float* __restrict__ x, const float* __restrict__ w,
    const float* __restrict__ bias, const float* __restrict__ st, float invN,
    float* __restrict__ y, float* __restrict__ stOut) {
  constexpr int HOUT = 2 * HIN;
  constexpr int QP2 = HIN * (HIN / 2);
  const int tid = threadIdx.x;
  const int cog = blockIdx.y * CO;

  __shared__ float lw[CO * CIN * 12];
  __shared__ float nrm[2][HASN ? CIN : 1];
  __shared__ float red[2][4][4];

  for (int i = tid; i < CIN * CO * 9; i += 256) {
    int ci = i / (CO * 9);
    int rem = i - ci * (CO * 9);
    int j = rem / 9, k = rem - j * 9;
    lw[(j * CIN + ci) * 12 + k] = w[((size_t)ci * COUT + cog) * 9 + rem];
  }
  if (HASN) {
    for (int c = tid; c < CIN; c += 256) {
      float m = st[c] * invN;
      float var = st[256 + c] * invN - m * m;
      float s = rsqrtf(var + EPS_BN);
      nrm[0][c] = s;
      nrm[1][c] = m * s;
    }
  }
  __syncthreads();

  const int idx = blockIdx.x * 256 + tid;
  const int p = idx % QP2;
  const int n = idx / QP2;
  const int y0 = p / (HIN / 2);
  const int x0 = (p % (HIN / 2)) * 2;
  const bool oky = (y0 + 1) < HIN;
  const bool okx = (x0 + 2) < HIN;
  const float* xn = x + (size_t)n * CIN * HIN * HIN;

  float acc[CO][8];
#pragma unroll
  for (int j = 0; j < CO; ++j) {
    const float b = bias[cog + j];
#pragma unroll
    for (int qq = 0; qq < 8; ++qq) acc[j][qq] = b;
  }

  float v[6];
  {
    const float* bp = xn + y0 * HIN + x0;
    const float s = HASN ? nrm[0][0] : 1.f;
    const float ms = HASN ? nrm[1][0] : 0.f;
    v[0] = fmaf(bp[0], s, -ms);
    v[1] = fmaf(bp[1], s, -ms);
    v[2] = okx ? fmaf(bp[2], s, -ms) : 0.f;
    v[3] = oky ? fmaf(bp[HIN], s, -ms) : 0.f;
    v[4] = oky ? fmaf(bp[HIN + 1], s, -ms) : 0.f;
    v[5] = (oky && okx) ? fmaf(bp[HIN + 2], s, -ms) : 0.f;
  }

  for (int ci = 0; ci < CIN; ++ci) {
    float vn[6];
    if (ci + 1 < CIN) {
      const float* bp = xn + (size_t)(ci + 1) * HIN * HIN + y0 * HIN + x0;
      const float s = HASN ? nrm[0][ci + 1] : 1.f;
      const float ms = HASN ? nrm[1][ci + 1] : 0.f;
      vn[0] = fmaf(bp[0], s, -ms);
      vn[1] = fmaf(bp[1], s, -ms);
      vn[2] = okx ? fmaf(bp[2], s, -ms) : 0.f;
      vn[3] = oky ? fmaf(bp[HIN], s, -ms) : 0.f;
      vn[4] = oky ? fmaf(bp[HIN + 1], s, -ms) : 0.f;
      vn[5] = (oky && okx) ? fmaf(bp[HIN + 2], s, -ms) : 0.f;
    }
#pragma unroll
    for (int j = 0; j < CO; ++j) {
      const float* wj = &lw[(j * CIN + ci) * 12];
      const float4 wa = *(const float4*)wj;
      const float4 wb = *(const float4*)(wj + 4);
      const float w8 = wj[8];
      const float w9[9] = {wa.x, wa.y, wa.z, wa.w, wb.x, wb.y, wb.z, wb.w, w8};
      acc[j][0] = fmaf(v[0], w9[4], acc[j][0]);
      acc[j][1] = fmaf(v[0], w9[5], fmaf(v[1], w9[3], acc[j][1]));
      acc[j][4] = fmaf(v[0], w9[7], fmaf(v[3], w9[1], acc[j][4]));
      acc[j][5] = fmaf(v[0], w9[8], fmaf(v[1], w9[6],
                   fmaf(v[3], w9[2], fmaf(v[4], w9[0], acc[j][5]))));
      acc[j][2] = fmaf(v[1], w9[4], acc[j][2]);
      acc[j][3] = fmaf(v[1], w9[5], fmaf(v[2], w9[3], acc[j][3]));
      acc[j][6] = fmaf(v[1], w9[7], fmaf(v[4], w9[1], acc[j][6]));
      acc[j][7] = fmaf(v[1], w9[8], fmaf(v[2], w9[6],
                   fmaf(v[4], w9[2], fmaf(v[5], w9[0], acc[j][7]))));
    }
    if (ci + 1 < CIN) {
#pragma unroll
      for (int t = 0; t < 6; ++t) v[t] = vn[t];
    }
  }

  const int wv = tid >> 6, ln = tid & 63;
#pragma unroll
  for (int j = 0; j < CO; ++j) {
    float o[8];
#pragma unroll
    for (int qq = 0; qq < 8; ++qq) o[qq] = lrelu(acc[j][qq]);
    float* yp = &y[((size_t)n * COUT + cog + j) * (HOUT * HOUT) +
                   (2 * y0) * HOUT + 2 * x0];
    *(float4*)yp = make_float4(o[0], o[1], o[2], o[3]);
    *(float4*)(yp + HOUT) = make_float4(o[4], o[5], o[6], o[7]);
    float s_ = 0.f, q_ = 0.f;
#pragma unroll
    for (int qq = 0; qq < 8; ++qq) { s_ += o[qq]; q_ += o[qq] * o[qq]; }
#pragma unroll
    for (int off = 32; off > 0; off >>= 1) {
      s_ += __shfl_down(s_, off);
      q_ += __shfl_down(q_, off);
    }
    if (ln == 0) { red[0][wv][j] = s_; red[1][wv][j] = q_; }
  }
  __syncthreads();
  if (tid < CO) {
    float S = red[0][0][tid] + red[0][1][tid] + red[0][2][tid] + red[0][3][tid];
    float Qq = red[1][0][tid] + red[1][1][tid] + red[1][2][tid] + red[1][3][tid];
    atomicAdd(&stOut[cog + tid], S);
    atomicAdd(&stOut[256 + cog + tid], Qq);
  }
}

// ---- final convT 3x3 stride1 pad1 + sigmoid(2a) (== 0.5+0.5*tanh(a)) ------
// thread: 3 channels x 2x2 pixel tile. LDS weights + raw-stat norm.
__global__ __launch_bounds__(256) void convt4_tanh(
    const float* __restrict__ x, const float* __restrict__ w,
    const float* __restrict__ bias, const float* __restrict__ st, float invN,
    float* __restrict__ out) {
  __shared__ float lw[3 * 32 * 12];
  __shared__ float nrm[2][32];
  const int tid = threadIdx.x;
  for (int i = tid; i < 32 * 27; i += 256) {
    int ci = i / 27, rem = i - ci * 27;
    int co = rem / 9, k = rem - co * 9;
    lw[(co * 32 + ci) * 12 + k] = w[i];
  }
  for (int c = tid; c < 32; c += 256) {
    float m = st[c] * invN;
    float var = st[256 + c] * invN - m * m;
    float s = rsqrtf(var + EPS_BN);
    nrm[0][c] = s;
    nrm[1][c] = m * s;
  }
  __syncthreads();

  const int idx = blockIdx.x * 256 + tid;
  const int p = idx & 1023;
  const int n = idx >> 10;
  const int y0 = (p >> 5) * 2;
  const int x0 = (p & 31) * 2;
  const float* xn = x + (size_t)n * 32 * 4096;

  bool okr[4], okc[4];
#pragma unroll
  for (int r = 0; r < 4; ++r) okr[r] = (unsigned)(y0 - 1 + r) < 64u;
#pragma unroll
  for (int c = 0; c < 4; ++c) okc[c] = (unsigned)(x0 - 1 + c) < 64u;

  float acc[3][4];
#pragma unroll
  for (int co = 0; co < 3; ++co) {
    const float b = bias[co];
#pragma unroll
    for (int qq = 0; qq < 4; ++qq) acc[co][qq] = b;
  }

  float v[4][4];
  {
    const float* xp = xn;
    const float s = nrm[0][0], ms = nrm[1][0];
#pragma unroll
    for (int r = 0; r < 4; ++r)
#pragma unroll
      for (int c = 0; c < 4; ++c)
        v[r][c] = (okr[r] && okc[c])
                      ? fmaf(xp[(y0 - 1 + r) * 64 + x0 - 1 + c], s, -ms) : 0.f;
  }

  for (int ci = 0; ci < 32; ++ci) {
    float vn[4][4];
    if (ci + 1 < 32) {
      const float* xp = xn + (ci + 1) * 4096;
      const float s = nrm[0][ci + 1], ms = nrm[1][ci + 1];
#pragma unroll
      for (int r = 0; r < 4; ++r)
#pragma unroll
        for (int c = 0; c < 4; ++c)
          vn[r][c] = (okr[r] && okc[c])
                         ? fmaf(xp[(y0 - 1 + r) * 64 + x0 - 1 + c], s, -ms) : 0.f;
    }
#pragma unroll
    for (int co = 0; co < 3; ++co) {
      const float* wj = &lw[(co * 32 + ci) * 12];
      const float4 wa = *(const float4*)wj;
      const float4 wb = *(const float4*)(wj + 4);
      const float w8 = wj[8];
      const float w9[9] = {wa.x, wa.y, wa.z, wa.w, wb.x, wb.y, wb.z, wb.w, w8};
#pragma unroll
      for (int dy = 0; dy < 2; ++dy)
#pragma unroll
        for (int dx = 0; dx < 2; ++dx)
#pragma unroll
          for (int ky = 0; ky < 3; ++ky)
#pragma unroll
            for (int kx = 0; kx < 3; ++kx)
              acc[co][dy * 2 + dx] = fmaf(v[dy + 2 - ky][dx + 2 - kx],
                                          w9[ky * 3 + kx], acc[co][dy * 2 + dx]);
    }
    if (ci + 1 < 32) {
#pragma unroll
      for (int r = 0; r < 4; ++r)
#pragma unroll
        for (int c = 0; c < 4; ++c) v[r][c] = vn[r][c];
    }
  }
#pragma unroll
  for (int co = 0; co < 3; ++co) {
    float o[4];
#pragma unroll
    for (int qq = 0; qq < 4; ++qq) o[qq] = 1.f / (1.f + __expf(-2.f * acc[co][qq]));
    float* op = &out[(((size_t)n * 3 + co) << 12) + y0 * 64 + x0];
    *(float2*)op = make_float2(o[0], o[1]);
    *(float2*)(op + 64) = make_float2(o[2], o[3]);
  }
}

// ---- tiled GEMM: C[M,N] = alpha * A[M,K] * B[N,K]^T (+bias, act) ---------
// 64x64 tile, BK=16, 256 threads, 4x4 micro-tile. Optional raw-stat norm on
// A (channel = k>>4, 256 channels). gridDim.z>1 => write raw partials to P.
__global__ __launch_bounds__(256) void gemm_abt(
    const float* __restrict__ A, const float* __restrict__ B,
    const float* __restrict__ bias, const float* __restrict__ stA, float invN,
    float* __restrict__ C, float* __restrict__ P, int K, int ldc, int col0,
    float alpha, int act) {
  __shared__ float As[16][68];
  __shared__ float Bsh[16][68];
  __shared__ float nrm[2][256];
  const int tid = threadIdx.x;
  if (stA) {
    const int c = tid;
    float m = stA[c] * invN;
    float var = stA[256 + c] * invN - m * m;
    float s = rsqrtf(var + EPS_BN);
    nrm[0][c] = s;
    nrm[1][c] = m * s;
  }
  __syncthreads();
  const int lm = tid >> 2, lk = (tid & 3) << 2;
  const int KS = gridDim.z;
  const int kChunk = K / KS;
  const int kStart = blockIdx.z * kChunk;
  const float* Arow = A + (size_t)(blockIdx.y * 64 + lm) * K + lk;
  const float* Brow = B + (size_t)(blockIdx.x * 64 + lm) * K + lk;
  float acc[4][4] = {};
  const int m0 = (tid >> 4) << 2, n0 = (tid & 15) << 2;

  for (int k0 = kStart; k0 < kStart + kChunk; k0 += 16) {
    float4 av = *(const float4*)(Arow + k0);
    float4 bv = *(const float4*)(Brow + k0);
    if (stA) {
      const int ch = (k0 + lk) >> 4;
      const float s = nrm[0][ch], ms = nrm[1][ch];
      av.x = fmaf(av.x, s, -ms); av.y = fmaf(av.y, s, -ms);
      av.z = fmaf(av.z, s, -ms); av.w = fmaf(av.w, s, -ms);
    }
    As[lk + 0][lm] = av.x; As[lk + 1][lm] = av.y;
    As[lk + 2][lm] = av.z; As[lk + 3][lm] = av.w;
    Bsh[lk + 0][lm] = bv.x; Bsh[lk + 1][lm] = bv.y;
    Bsh[lk + 2][lm] = bv.z; Bsh[lk + 3][lm] = bv.w;
    __syncthreads();
#pragma unroll
    for (int kk = 0; kk < 16; ++kk) {
      const float4 a = *(const float4*)&As[kk][m0];
      const float4 b = *(const float4*)&Bsh[kk][n0];
      acc[0][0] = fmaf(a.x, b.x, acc[0][0]); acc[0][1] = fmaf(a.x, b.y, acc[0][1]);
      acc[0][2] = fmaf(a.x, b.z, acc[0][2]); acc[0][3] = fmaf(a.x, b.w, acc[0][3]);
      acc[1][0] = fmaf(a.y, b.x, acc[1][0]); acc[1][1] = fmaf(a.y, b.y, acc[1][1]);
      acc[1][2] = fmaf(a.y, b.z, acc[1][2]); acc[1][3] = fmaf(a.y, b.w, acc[1][3]);
      acc[2][0] = fmaf(a.z, b.x, acc[2][0]); acc[2][1] = fmaf(a.z, b.y, acc[2][1]);
      acc[2][2] = fmaf(a.z, b.z, acc[2][2]); acc[2][3] = fmaf(a.z, b.w, acc[2][3]);
      acc[3][0] = fmaf(a.w, b.x, acc[3][0]); acc[3][1] = fmaf(a.w, b.y, acc[3][1]);
      acc[3][2] = fmaf(a.w, b.z, acc[3][2]); acc[3][3] = fmaf(a.w, b.w, acc[3][3]);
    }
    __syncthreads();
  }

  const int gm = blockIdx.y * 64 + m0;
  const int gn = blockIdx.x * 64 + n0;
  if (KS == 1) {
#pragma unroll
    for (int i = 0; i < 4; ++i) {
      float4 o;
      o.x = alpha * acc[i][0] + bias[gn + 0];
      o.y = alpha * acc[i][1] + bias[gn + 1];
      o.z = alpha * acc[i][2] + bias[gn + 2];
      o.w = alpha * acc[i][3] + bias[gn + 3];
      if (act == 1) {
        o.x = fmaxf(o.x, 0.f); o.y = fmaxf(o.y, 0.f);
        o.z = fmaxf(o.z, 0.f); o.w = fmaxf(o.w, 0.f);
      }
      *(float4*)&C[(size_t)(gm + i) * ldc + col0 + gn] = o;
    }
  } else {
    const int M = gridDim.y * 64, N = gridDim.x * 64;
#pragma unroll
    for (int i = 0; i < 4; ++i)
      *(float4*)&P[((size_t)blockIdx.z * M + gm + i) * N + gn] =
          make_float4(acc[i][0], acc[i][1], acc[i][2], acc[i][3]);
  }
}

// ---- reduce k-split partials: C = act(alpha * sum_z P + bias) ------------
__global__ __launch_bounds__(256) void gemm_reduce(
    const float* __restrict__ P, float* __restrict__ C,
    const float* __restrict__ bias, int M, int N, int ldc, int col0,
    float alpha, int act, int KS) {
  const int idx = blockIdx.x * 256 + threadIdx.x;
  if (idx >= M * N) return;
  const int m = idx / N, n = idx % N;
  float s = 0.f;
  for (int z = 0; z < KS; ++z) s += P[((size_t)z * M + m) * N + n];
  float v = alpha * s + bias[n];
  if (act == 1) v = fmaxf(v, 0.f);
  C[(size_t)m * ldc + col0 + n] = v;
}

// ---- per-row squared norm of codebook: csq[k] = ||cb[k]||^2 --------------
__global__ __launch_bounds__(256) void rowsq(const float* __restrict__ cb,
                                             float* __restrict__ csq) {
  const int row = blockIdx.x * 4 + (threadIdx.x >> 6);
  const int ln = threadIdx.x & 63;
  const float4 v = ((const float4*)(cb + (size_t)row * 256))[ln];
  float s = v.x * v.x + v.y * v.y + v.z * v.z + v.w * v.w;
#pragma unroll
  for (int off = 32; off > 0; off >>= 1) s += __shfl_down(s, off);
  if (ln == 0) csq[row] = s;
}

// ---- argmin over d2 rows (first-min tie-break like jnp.argmin) -----------
__global__ __launch_bounds__(256) void argmin_d2(const float* __restrict__ d2,
                                                 int* __restrict__ idx) {
  const int b = blockIdx.x, t = threadIdx.x;
  const float* row = d2 + (size_t)b * 8192;
  float best = 3.4e38f;
  int bi = 0x7fffffff;
  for (int k = t; k < 8192; k += 256) {
    const float v = row[k];
    if (v < best) { best = v; bi = k; }
  }
  __shared__ float bval[256];
  __shared__ int bidx[256];
  bval[t] = best; bidx[t] = bi;
  __syncthreads();
  for (int s = 128; s > 0; s >>= 1) {
    if (t < s) {
      const float ov = bval[t + s];
      const int oi = bidx[t + s];
      if (ov < bval[t] || (ov == bval[t] && oi < bidx[t])) {
        bval[t] = ov; bidx[t] = oi;
      }
    }
    __syncthreads();
  }
  if (t == 0) idx[b] = bidx[0];
}

// ---- gather z_q = cb[idx[b]] and accumulate sum((z_e - z_q)^2) -----------
__global__ __launch_bounds__(256) void vq_gather_loss(
    const float* __restrict__ ze, const float* __restrict__ cb,
    const int* __restrict__ idx, float* __restrict__ zq,
    float* __restrict__ lossacc) {
  const int b = blockIdx.x, d = threadIdx.x;
  const int i = b * 256 + d;
  const float q = cb[(size_t)idx[b] * 256 + d];
  zq[i] = q;
  const float df = ze[i] - q;
  float v = df * df;
  __shared__ float sh[256];
  sh[d] = v;
  __syncthreads();
  for (int s = 128; s > 0; s >>= 1) {
    if (d < s) sh[d] += sh[d + s];
    __syncthreads();
  }
  if (d == 0) atomicAdd(lossacc, sh[0]);
}

__global__ void write_loss(const float* __restrict__ lossacc,
                           float* __restrict__ out) {
  out[0] = 2.f * lossacc[0];
}

// ---------------------------------------------------------------------------
extern "C" void kernel_launch(void* const* d_in, const int* in_sizes, int n_in,
                              void* d_out, int out_size, void* d_ws,
                              size_t ws_size, hipStream_t stream) {
  const float* x = (const float*)d_in[0];
  const float* ew1 = (const float*)d_in[1];
  const float* eb1 = (const float*)d_in[2];
  const float* ew2 = (const float*)d_in[3];
  const float* eb2 = (const float*)d_in[4];
  const float* ew3 = (const float*)d_in[5];
  const float* eb3 = (const float*)d_in[6];
  const float* ew4 = (const float*)d_in[7];
  const float* eb4 = (const float*)d_in[8];
  const float* wmu = (const float*)d_in[9];
  const float* bmu = (const float*)d_in[10];
  const float* wcov = (const float*)d_in[11];
  const float* bcov = (const float*)d_in[12];
  const float* cb = (const float*)d_in[13];
  const float* wfc = (const float*)d_in[14];
  const float* bfc = (const float*)d_in[15];
  const float* wt1 = (const float*)d_in[16];
  const float* bt1 = (const float*)d_in[17];
  const float* wt2 = (const float*)d_in[18];
  const float* bt2 = (const float*)d_in[19];
  const float* wt3 = (const float*)d_in[20];
  const float* bt3 = (const float*)d_in[21];
  const float* wt31 = (const float*)d_in[22];
  const float* bt31 = (const float*)d_in[23];
  const float* wt4 = (const float*)d_in[24];
  const float* bt4 = (const float*)d_in[25];

  float* ws = (float*)d_ws;
  float* a1 = ws;              // [256,32,32,32]  8388608  (reused as g3)
  float* a2 = a1 + 8388608;    // [256,64,16,16]  4194304  (reused as g2)
  float* a3 = a2 + 4194304;    // [256,128,8,8]   2097152  (reused as g1)
  float* a4 = a3 + 2097152;    // [256,256,4,4]   1048576  (reused as g0)
  float* g31 = a4 + 1048576;   // [256,32,64,64] 33554432
  float* d2 = g31;             // [256,8192] aliases g31 (dead before t1)
  float* P = g31 + 2097152;    // k-split partials 8*256*128
  float* csq = g31 + 2359296;  // 8192
  float* ze = g31 + 33554432;  // [256,256]
  float* zq = ze + 65536;
  float* stats = zq + 65536;   // 8 layers x 512
  float* lossacc = stats + 4096;
  int* idx = (int*)(lossacc + 4);
  float* g3 = a1;
  float* g2 = a2;
  float* g1 = a3;
  float* g0 = a4;

  float* st0 = stats + 0 * 512;
  float* st1 = stats + 1 * 512;
  float* st2 = stats + 2 * 512;
  float* st3 = stats + 3 * 512;
  float* st4 = stats + 4 * 512;
  float* st5 = stats + 5 * 512;
  float* st6 = stats + 6 * 512;
  float* st7 = stats + 7 * 512;

  hipMemsetAsync(stats, 0, (4096 + 8) * sizeof(float), stream);
  rowsq<<<2048, 256, 0, stream>>>(cb, csq);  // independent; do it early

  // ---- encoder ----
  conv_s2<3, 64, 32, 4, false><<<dim3(256, 8), 256, 0, stream>>>(
      x, ew1, eb1, nullptr, 0.f, a1, st0);
  conv_s2<32, 32, 64, 4, true><<<dim3(64, 16), 256, 0, stream>>>(
      a1, ew2, eb2, st0, 1.f / (256.f * 1024.f), a2, st1);
  conv_s2<64, 16, 128, 4, true><<<dim3(16, 32), 256, 0, stream>>>(
      a2, ew3, eb3, st1, 1.f / (256.f * 256.f), a3, st2);
  conv_s2<128, 8, 256, 2, true><<<dim3(4, 128), 256, 0, stream>>>(
      a3, ew4, eb4, st2, 1.f / (256.f * 64.f), a4, st3);

  // ---- encoder FC (k-split GEMM, deterministic reduce) ----
  gemm_abt<<<dim3(2, 4, 8), 256, 0, stream>>>(a4, wmu, nullptr, st3,
                                              1.f / 4096.f, nullptr, P, 4096,
                                              0, 0, 1.f, 0);
  gemm_reduce<<<128, 256, 0, stream>>>(P, ze, bmu, 256, 128, 256, 0, 1.f, 0, 8);
  gemm_abt<<<dim3(2, 4, 8), 256, 0, stream>>>(a4, wcov, nullptr, st3,
                                              1.f / 4096.f, nullptr, P, 4096,
                                              0, 0, 1.f, 0);
  gemm_reduce<<<128, 256, 0, stream>>>(P, ze, bcov, 256, 128, 256, 128, 1.f, 1, 8);

  // ---- VQ: d2[b,k] = ||c_k||^2 - 2 z.c (row-constant ||z||^2 dropped) ----
  gemm_abt<<<dim3(128, 4, 1), 256, 0, stream>>>(ze, cb, csq, nullptr, 0.f, d2,
                                                nullptr, 256, 8192, 0, -2.f, 0);
  argmin_d2<<<256, 256, 0, stream>>>(d2, idx);
  vq_gather_loss<<<256, 256, 0, stream>>>(ze, cb, idx, zq, lossacc);

  // ---- decoder FC ----
  gemm_abt<<<dim3(64, 4, 1), 256, 0, stream>>>(zq, wfc, bfc, nullptr, 0.f, g0,
                                               nullptr, 256, 4096, 0, 1.f, 0);

  // ---- decoder ----
  convt_s2<256, 4, 128, 2, false><<<dim3(8, 64), 256, 0, stream>>>(
      g0, wt1, bt1, nullptr, 0.f, g1, st4);
  convt_s2<128, 8, 64, 4, true><<<dim3(32, 16), 256, 0, stream>>>(
      g1, wt2, bt2, st4, 1.f / (256.f * 64.f), g2, st5);
  convt_s2<64, 16, 32, 4, true><<<dim3(128, 8), 256, 0, stream>>>(
      g2, wt3, bt3, st5, 1.f / (256.f * 256.f), g3, st6);
  convt_s2<32, 32, 32, 4, true><<<dim3(512, 8), 256, 0, stream>>>(
      g3, wt31, bt31, st6, 1.f / (256.f * 1024.f), g31, st7);

  convt4_tanh<<<1024, 256, 0, stream>>>(g31, wt4, bt4, st7,
                                        1.f / (256.f * 4096.f), (float*)d_out);
  write_loss<<<1, 1, 0, stream>>>(lossacc, (float*)d_out + 3145728);
}

// Round 4
// 1345.358 us; speedup vs baseline: 7.9037x; 1.4748x over previous
//
#include <hip/hip_runtime.h>
#include <cmath>

// ---------------------------------------------------------------------------
// VQ-VAE forward, fp32. B=256, C=3, HW=64, D=256, K=8192, LAT=128
// R3: all mid convs as implicit-GEMM in NHWC (im2col gather fused in A-stage,
// convT as 4 parity sub-GEMMs via blockIdx.z), weights pre-transposed to
// [k][co] for coalesced B staging, BN-norm fused into gather, bias+LeakyReLU+
// BN-stats fused into epilogue. conv1 & final tanh-conv direct (NHWC).
// ---------------------------------------------------------------------------

#define EPS_BN 1e-5f

__device__ __forceinline__ float lrelu(float v) { return v >= 0.f ? v : 0.01f * v; }

// ======================= weight transposes (once per launch) ===============
// conv weights (COUT,CIN,3,3) -> wT[(t*CIN+ci)*COUT+co], t=ky*3+kx
__global__ __launch_bounds__(256) void tr_convw(const float* __restrict__ w,
                                                float* __restrict__ wT,
                                                int CIN, int COUT, int total) {
  int i = blockIdx.x * 256 + threadIdx.x;
  if (i >= total) return;
  int co = i % COUT;
  int tmp = i / COUT;
  int ci = tmp % CIN;
  int t = tmp / CIN;
  wT[i] = w[((size_t)co * CIN + ci) * 9 + t];
}

// convT weights (CIN,COUT,3,3) -> parity-concat wT, sizes {1,2,2,4}*CIN*COUT
__global__ __launch_bounds__(256) void tr_convtw(const float* __restrict__ w,
                                                 float* __restrict__ wT,
                                                 int CIN, int COUT, int total) {
  int i = blockIdx.x * 256 + threadIdx.x;
  if (i >= total) return;
  int u = i / (CIN * COUT);
  int rem = i % (CIN * COUT);
  int ci = rem / COUT, co = rem % COUT;
  int ky, kx;
  if (u == 0) { ky = 1; kx = 1; }                       // parity (0,0)
  else if (u <= 2) { ky = 1; kx = (u == 1) ? 0 : 2; }   // parity (0,1)
  else if (u <= 4) { ky = (u == 3) ? 0 : 2; kx = 1; }   // parity (1,0)
  else { int t = u - 5; ky = (t >> 1) ? 2 : 0; kx = (t & 1) ? 2 : 0; }  // (1,1)
  wT[i] = w[((size_t)ci * COUT + co) * 9 + ky * 3 + kx];
}

// wmu/wcov [128,4096]: permute K from (c,y,x) to (y,x,c)
__global__ __launch_bounds__(256) void tr_permk(const float* __restrict__ in,
                                                float* __restrict__ out) {
  int i = blockIdx.x * 256 + threadIdx.x;  // 128*4096
  int j = i >> 12, k = i & 4095;
  out[(size_t)j * 4096 + ((k & 15) * 256 + (k >> 4))] = in[i];
}

// wfc [4096,256] + bfc: permute ROWS from (c,y,x) to (y,x,c)
__global__ __launch_bounds__(256) void tr_fcdec(const float* __restrict__ in,
                                                const float* __restrict__ bin,
                                                float* __restrict__ out,
                                                float* __restrict__ bout) {
  int i = blockIdx.x * 256 + threadIdx.x;  // 4096*256
  int k = i >> 8, d = i & 255;
  int kp = (k & 15) * 256 + (k >> 4);
  out[(size_t)kp * 256 + d] = in[i];
  if (d == 0) bout[kp] = bin[k];
}

// ======================= implicit-GEMM conv / convT ========================
// MODE 0: stride-2 conv 3x3 pad1.  MODE 1: convT stride-2 pad1 outpad1,
// blockIdx.z = parity (py=z>>1, px=z&1). NHWC activations.
// C = lrelu(A*W + bias); BN-stat partials atomically accumulated to stOut.
template <int TM, int TN, int MODE, int IH, int CIN, int COUT, bool HASN>
__global__ __launch_bounds__(256) void gemmconv(
    const float* __restrict__ X, const float* __restrict__ WT,
    const float* __restrict__ bias, const float* __restrict__ st, float invN,
    float* __restrict__ Y, float* __restrict__ stOut) {
  constexpr int OH = (MODE == 0) ? IH / 2 : 2 * IH;
  constexpr int MR = TM / 16, NR = TN / 16;
  constexpr int LDA = TM + 8, LDB = TN + 8;
  __shared__ float As[16][LDA];
  __shared__ float Bs[16][LDB];
  __shared__ float nrm0[HASN ? CIN : 4], nrm1[HASN ? CIN : 4];
  __shared__ float redS[16][LDB], redQ[16][LDB];
  const int tid = threadIdx.x;
  if (HASN) {
    for (int c = tid; c < CIN; c += 256) {
      float m = st[c] * invN;
      float var = st[256 + c] * invN - m * m;
      float s = rsqrtf(var + EPS_BN);
      nrm0[c] = s;
      nrm1[c] = m * s;
    }
    __syncthreads();
  }
  int py = 0, px = 0, nx = 1, K = 9 * CIN;
  int dy0 = 0, dy1 = 0, dx0 = 0, dx1 = 0;
  const float* W = WT;
  if (MODE == 1) {
    const int pz = blockIdx.z;
    py = pz >> 1;
    px = pz & 1;
    nx = px ? 2 : 1;
    const int ny = py ? 2 : 1;
    if (py) { dy0 = 1; dy1 = 0; }
    if (px) { dx0 = 1; dx1 = 0; }
    K = ny * nx * CIN;
    const int pre[4] = {0, 1, 3, 5};
    W = WT + (size_t)pre[pz] * CIN * COUT;
  }
  const int gyTM = blockIdx.y * TM;
  const int gxTN = blockIdx.x * TN;

  // precompute this thread's A-stage chunks (row -> image coords)
  constexpr int NCH = (TM * 4 + 255) / 256;
  int chRow[NCH], chQ4[NCH], chIY[NCH], chIX[NCH];
  size_t chNB[NCH];
  bool chV[NCH];
#pragma unroll
  for (int c = 0; c < NCH; ++c) {
    const int i = tid + c * 256;
    chV[c] = i < TM * 4;
    if (chV[c]) {
      const int row = i >> 2;
      chRow[c] = row;
      chQ4[c] = (i & 3) * 4;
      const int m = gyTM + row;
      if (MODE == 0) {
        const int ni = m / (OH * OH), r = m % (OH * OH);
        chNB[c] = (size_t)ni * IH * IH;
        chIY[c] = 2 * (r / OH) - 1;
        chIX[c] = 2 * (r % OH) - 1;
      } else {
        const int ni = m / (IH * IH), r = m % (IH * IH);
        chNB[c] = (size_t)ni * IH * IH;
        chIY[c] = r / IH;
        chIX[c] = r % IH;
      }
    }
  }
  const int m0 = (tid >> 4) * MR, n0 = (tid & 15) * NR;
  float acc[MR][NR];
#pragma unroll
  for (int i = 0; i < MR; ++i)
#pragma unroll
    for (int j = 0; j < NR; ++j) acc[i][j] = 0.f;

  for (int k0 = 0; k0 < K; k0 += 16) {
    const int t = k0 / CIN, ci0 = k0 - t * CIN;
    int ky, kx;
    if (MODE == 0) {
      ky = t / 3;
      kx = t - ky * 3;
    } else {
      const int kyi = t / nx, kxi = t - kyi * nx;
      ky = kyi ? dy1 : dy0;
      kx = kxi ? dx1 : dx0;
    }
#pragma unroll
    for (int c = 0; c < NCH; ++c) {
      if (chV[c]) {
        const int iy = chIY[c] + ky, ix = chIX[c] + kx;
        const bool ok =
            ((unsigned)iy < (unsigned)IH) && ((unsigned)ix < (unsigned)IH);
        float4 v = make_float4(0.f, 0.f, 0.f, 0.f);
        if (ok)
          v = *(const float4*)&X[(chNB[c] + iy * IH + ix) * CIN + ci0 + chQ4[c]];
        if (HASN) {
          const int cc = ci0 + chQ4[c];
          v.x = fmaf(v.x, nrm0[cc + 0], -nrm1[cc + 0]);
          v.y = fmaf(v.y, nrm0[cc + 1], -nrm1[cc + 1]);
          v.z = fmaf(v.z, nrm0[cc + 2], -nrm1[cc + 2]);
          v.w = fmaf(v.w, nrm0[cc + 3], -nrm1[cc + 3]);
        }
        const int kq = chQ4[c], rw = chRow[c];
        As[kq + 0][rw] = v.x;
        As[kq + 1][rw] = v.y;
        As[kq + 2][rw] = v.z;
        As[kq + 3][rw] = v.w;
      }
    }
#pragma unroll
    for (int c = 0; c < (TN * 4 + 255) / 256; ++c) {
      const int i = tid + c * 256;
      if (i < TN * 4) {
        const int kk = i / (TN / 4);
        const int nc = (i % (TN / 4)) * 4;
        *(float4*)&Bs[kk][nc] =
            *(const float4*)&W[(size_t)(k0 + kk) * COUT + gxTN + nc];
      }
    }
    __syncthreads();
#pragma unroll
    for (int kk = 0; kk < 16; ++kk) {
      float a[MR], b[NR];
      if constexpr (MR == 2) {
        const float2 av = *(const float2*)&As[kk][m0];
        a[0] = av.x; a[1] = av.y;
      } else if constexpr (MR == 4) {
        const float4 av = *(const float4*)&As[kk][m0];
        a[0] = av.x; a[1] = av.y; a[2] = av.z; a[3] = av.w;
      } else {
        const float4 av = *(const float4*)&As[kk][m0];
        const float4 aw = *(const float4*)&As[kk][m0 + 4];
        a[0] = av.x; a[1] = av.y; a[2] = av.z; a[3] = av.w;
        a[4] = aw.x; a[5] = aw.y; a[6] = aw.z; a[7] = aw.w;
      }
      if constexpr (NR == 2) {
        const float2 bv = *(const float2*)&Bs[kk][n0];
        b[0] = bv.x; b[1] = bv.y;
      } else {
        const float4 bv = *(const float4*)&Bs[kk][n0];
        b[0] = bv.x; b[1] = bv.y; b[2] = bv.z; b[3] = bv.w;
      }
#pragma unroll
      for (int i = 0; i < MR; ++i)
#pragma unroll
        for (int j = 0; j < NR; ++j) acc[i][j] = fmaf(a[i], b[j], acc[i][j]);
    }
    __syncthreads();
  }

  // epilogue: bias + lrelu + store + BN-stat partials
  float bv[NR], colS[NR], colQ[NR];
#pragma unroll
  for (int j = 0; j < NR; ++j) {
    bv[j] = bias[gxTN + n0 + j];
    colS[j] = 0.f;
    colQ[j] = 0.f;
  }
#pragma unroll
  for (int i = 0; i < MR; ++i) {
    const int m = gyTM + m0 + i;
    float o[NR];
#pragma unroll
    for (int j = 0; j < NR; ++j) {
      o[j] = lrelu(acc[i][j] + bv[j]);
      colS[j] += o[j];
      colQ[j] += o[j] * o[j];
    }
    size_t addr;
    if (MODE == 0) {
      const int ni = m / (OH * OH), r = m % (OH * OH);
      addr = (((size_t)ni * OH + r / OH) * OH + r % OH) * COUT + gxTN + n0;
    } else {
      const int ni = m / (IH * IH), r = m % (IH * IH);
      const int oy = 2 * (r / IH) + py, ox = 2 * (r % IH) + px;
      addr = (((size_t)ni * OH + oy) * OH + ox) * COUT + gxTN + n0;
    }
    if constexpr (NR == 4)
      *(float4*)&Y[addr] = make_float4(o[0], o[1], o[2], o[3]);
    else
      *(float2*)&Y[addr] = make_float2(o[0], o[1]);
  }
  const int rgrp = tid >> 4;
#pragma unroll
  for (int j = 0; j < NR; ++j) {
    redS[rgrp][n0 + j] = colS[j];
    redQ[rgrp][n0 + j] = colQ[j];
  }
  __syncthreads();
  if (tid < TN) {
    float S = 0.f, Q = 0.f;
#pragma unroll
    for (int r = 0; r < 16; ++r) {
      S += redS[r][tid];
      Q += redQ[r][tid];
    }
    atomicAdd(&stOut[gxTN + tid], S);
    atomicAdd(&stOut[256 + gxTN + tid], Q);
  }
}

// ======================= conv1 (CIN=3), NCHW in -> NHWC out ================
// thread: 4 co x 2x2 px. grid (256, 8).
__global__ __launch_bounds__(256) void conv1(
    const float* __restrict__ x, const float* __restrict__ w,
    const float* __restrict__ bias, float* __restrict__ y,
    float* __restrict__ st) {
  __shared__ float lw[4 * 3 * 12];
  __shared__ float red[2][4][4];
  const int tid = threadIdx.x;
  const int cog = blockIdx.y * 4;
  for (int i = tid; i < 4 * 27; i += 256) {
    int cor = i / 27, rem = i % 27;
    lw[(cor * 3 + rem / 9) * 12 + rem % 9] = w[cog * 27 + i];
  }
  __syncthreads();
  const int idx = blockIdx.x * 256 + tid;
  const int q = idx & 255;
  const int n = idx >> 8;
  const int qy = q >> 4, qx = q & 15;
  const int iy0 = 4 * qy - 1, ix0 = 4 * qx - 1;
  const float* xn = x + (size_t)n * 3 * 4096;
  bool okr[5], okc[5];
#pragma unroll
  for (int r = 0; r < 5; ++r) okr[r] = (unsigned)(iy0 + r) < 64u;
#pragma unroll
  for (int c = 0; c < 5; ++c) okc[c] = (unsigned)(ix0 + c) < 64u;

  float acc[4][4];
#pragma unroll
  for (int j = 0; j < 4; ++j) {
    const float b = bias[cog + j];
#pragma unroll
    for (int p = 0; p < 4; ++p) acc[j][p] = b;
  }
#pragma unroll
  for (int ci = 0; ci < 3; ++ci) {
    const float* xp = xn + ci * 4096;
    float v[5][5];
#pragma unroll
    for (int r = 0; r < 5; ++r)
#pragma unroll
      for (int c = 0; c < 5; ++c)
        v[r][c] = (okr[r] && okc[c]) ? xp[(iy0 + r) * 64 + ix0 + c] : 0.f;
#pragma unroll
    for (int j = 0; j < 4; ++j) {
      const float* wj = &lw[(j * 3 + ci) * 12];
#pragma unroll
      for (int dy = 0; dy < 2; ++dy)
#pragma unroll
        for (int dx = 0; dx < 2; ++dx)
#pragma unroll
          for (int ky = 0; ky < 3; ++ky)
#pragma unroll
            for (int kx = 0; kx < 3; ++kx)
              acc[j][dy * 2 + dx] = fmaf(v[2 * dy + ky][2 * dx + kx],
                                         wj[ky * 3 + kx], acc[j][dy * 2 + dx]);
    }
  }
  const int wv = tid >> 6, ln = tid & 63;
  float sS[4], sQ[4];
#pragma unroll
  for (int j = 0; j < 4; ++j) { sS[j] = 0.f; sQ[j] = 0.f; }
#pragma unroll
  for (int dy = 0; dy < 2; ++dy)
#pragma unroll
    for (int dx = 0; dx < 2; ++dx) {
      float4 o;
      o.x = lrelu(acc[0][dy * 2 + dx]);
      o.y = lrelu(acc[1][dy * 2 + dx]);
      o.z = lrelu(acc[2][dy * 2 + dx]);
      o.w = lrelu(acc[3][dy * 2 + dx]);
      *(float4*)&y[(((size_t)n * 32 + 2 * qy + dy) * 32 + 2 * qx + dx) * 32 +
                   cog] = o;
      sS[0] += o.x; sS[1] += o.y; sS[2] += o.z; sS[3] += o.w;
      sQ[0] += o.x * o.x; sQ[1] += o.y * o.y;
      sQ[2] += o.z * o.z; sQ[3] += o.w * o.w;
    }
#pragma unroll
  for (int j = 0; j < 4; ++j) {
    float s_ = sS[j], q_ = sQ[j];
#pragma unroll
    for (int off = 32; off > 0; off >>= 1) {
      s_ += __shfl_down(s_, off);
      q_ += __shfl_down(q_, off);
    }
    if (ln == 0) { red[0][wv][j] = s_; red[1][wv][j] = q_; }
  }
  __syncthreads();
  if (tid < 4) {
    const int j = tid;
    float S = red[0][0][j] + red[0][1][j] + red[0][2][j] + red[0][3][j];
    float Q = red[1][0][j] + red[1][1][j] + red[1][2][j] + red[1][3][j];
    atomicAdd(&st[cog + j], S);
    atomicAdd(&st[256 + cog + j], Q);
  }
}

// ======================= final convT 3x3 s1 p1 + tanh, NHWC in, NCHW out ===
// thread: 3 co x 2x2 px. grid 1024 blocks.
__global__ __launch_bounds__(256) void convt4_tanh(
    const float* __restrict__ x, const float* __restrict__ w,
    const float* __restrict__ bias, const float* __restrict__ st, float invN,
    float* __restrict__ out) {
  __shared__ float lw[9 * 32 * 3];  // [t][ci][co]
  __shared__ float s0[32], s1[32];
  const int tid = threadIdx.x;
  for (int i = tid; i < 864; i += 256) {
    int t = i / 96, rem = i % 96;
    int ci = rem / 3, co = rem % 3;
    lw[i] = w[((size_t)ci * 3 + co) * 9 + t];
  }
  for (int c = tid; c < 32; c += 256) {
    float m = st[c] * invN;
    float var = st[256 + c] * invN - m * m;
    float s = rsqrtf(var + EPS_BN);
    s0[c] = s;
    s1[c] = m * s;
  }
  __syncthreads();
  const int idx = blockIdx.x * 256 + tid;
  const int p = idx & 1023;
  const int n = idx >> 10;
  const int y0 = (p >> 5) * 2;
  const int x0 = (p & 31) * 2;
  const float* xg = x + (size_t)n * 64 * 64 * 32;
  bool okr[4], okc[4];
#pragma unroll
  for (int r = 0; r < 4; ++r) okr[r] = (unsigned)(y0 - 1 + r) < 64u;
#pragma unroll
  for (int c = 0; c < 4; ++c) okc[c] = (unsigned)(x0 - 1 + c) < 64u;

  float acc[3][4];
#pragma unroll
  for (int co = 0; co < 3; ++co) {
    const float b = bias[co];
#pragma unroll
    for (int q = 0; q < 4; ++q) acc[co][q] = b;
  }
  for (int c8 = 0; c8 < 8; ++c8) {
    const int cb = c8 * 4;
    float4 win[4][4];
#pragma unroll
    for (int r = 0; r < 4; ++r)
#pragma unroll
      for (int c = 0; c < 4; ++c) {
        float4 v = make_float4(0.f, 0.f, 0.f, 0.f);
        if (okr[r] && okc[c]) {
          v = *(const float4*)&xg[(((size_t)(y0 - 1 + r)) * 64 + x0 - 1 + c) *
                                      32 + cb];
          v.x = fmaf(v.x, s0[cb + 0], -s1[cb + 0]);
          v.y = fmaf(v.y, s0[cb + 1], -s1[cb + 1]);
          v.z = fmaf(v.z, s0[cb + 2], -s1[cb + 2]);
          v.w = fmaf(v.w, s0[cb + 3], -s1[cb + 3]);
        }
        win[r][c] = v;
      }
#pragma unroll
    for (int t = 0; t < 9; ++t) {
      const int ky = t / 3, kx = t % 3;
#pragma unroll
      for (int co = 0; co < 3; ++co) {
        const float w0 = lw[t * 96 + (cb + 0) * 3 + co];
        const float w1 = lw[t * 96 + (cb + 1) * 3 + co];
        const float w2 = lw[t * 96 + (cb + 2) * 3 + co];
        const float w3 = lw[t * 96 + (cb + 3) * 3 + co];
#pragma unroll
        for (int dy = 0; dy < 2; ++dy)
#pragma unroll
          for (int dx = 0; dx < 2; ++dx) {
            const float4 v = win[dy + 2 - ky][dx + 2 - kx];
            float a = acc[co][dy * 2 + dx];
            a = fmaf(v.x, w0, a);
            a = fmaf(v.y, w1, a);
            a = fmaf(v.z, w2, a);
            a = fmaf(v.w, w3, a);
            acc[co][dy * 2 + dx] = a;
          }
      }
    }
  }
#pragma unroll
  for (int co = 0; co < 3; ++co) {
    float o[4];
#pragma unroll
    for (int q = 0; q < 4; ++q) o[q] = 1.f / (1.f + __expf(-2.f * acc[co][q]));
    float* op = &out[(((size_t)n * 3 + co) << 12) + y0 * 64 + x0];
    *(float2*)op = make_float2(o[0], o[1]);
    *(float2*)(op + 64) = make_float2(o[2], o[3]);
  }
}

// ======================= dense GEMM (fc / VQ distance) =====================
// C[M,N] = alpha*A[M,K]*B[N,K]^T (+bias, act). Optional NHWC BN-norm on A
// (channel = k & 255). gridDim.z>1 => raw partials to P.
__global__ __launch_bounds__(256) void gemm_abt(
    const float* __restrict__ A, const float* __restrict__ B,
    const float* __restrict__ bias, const float* __restrict__ stA, float invN,
    float* __restrict__ C, float* __restrict__ P, int K, int ldc, int col0,
    float alpha, int act) {
  __shared__ float As[16][68];
  __shared__ float Bsh[16][68];
  __shared__ float nrm[2][256];
  const int tid = threadIdx.x;
  if (stA) {
    const int c = tid;
    float m = stA[c] * invN;
    float var = stA[256 + c] * invN - m * m;
    float s = rsqrtf(var + EPS_BN);
    nrm[0][c] = s;
    nrm[1][c] = m * s;
    __syncthreads();
  }
  const int lm = tid >> 2, lk = (tid & 3) << 2;
  const int KS = gridDim.z;
  const int kChunk = K / KS;
  const int kStart = blockIdx.z * kChunk;
  const float* Arow = A + (size_t)(blockIdx.y * 64 + lm) * K + lk;
  const float* Brow = B + (size_t)(blockIdx.x * 64 + lm) * K + lk;
  float acc[4][4] = {};
  const int m0 = (tid >> 4) << 2, n0 = (tid & 15) << 2;

  for (int k0 = kStart; k0 < kStart + kChunk; k0 += 16) {
    float4 av = *(const float4*)(Arow + k0);
    float4 bv = *(const float4*)(Brow + k0);
    if (stA) {
      const int cc = (k0 + lk) & 255;
      av.x = fmaf(av.x, nrm[0][cc + 0], -nrm[1][cc + 0]);
      av.y = fmaf(av.y, nrm[0][cc + 1], -nrm[1][cc + 1]);
      av.z = fmaf(av.z, nrm[0][cc + 2], -nrm[1][cc + 2]);
      av.w = fmaf(av.w, nrm[0][cc + 3], -nrm[1][cc + 3]);
    }
    As[lk + 0][lm] = av.x; As[lk + 1][lm] = av.y;
    As[lk + 2][lm] = av.z; As[lk + 3][lm] = av.w;
    Bsh[lk + 0][lm] = bv.x; Bsh[lk + 1][lm] = bv.y;
    Bsh[lk + 2][lm] = bv.z; Bsh[lk + 3][lm] = bv.w;
    __syncthreads();
#pragma unroll
    for (int kk = 0; kk < 16; ++kk) {
      const float4 a = *(const float4*)&As[kk][m0];
      const float4 b = *(const float4*)&Bsh[kk][n0];
      acc[0][0] = fmaf(a.x, b.x, acc[0][0]); acc[0][1] = fmaf(a.x, b.y, acc[0][1]);
      acc[0][2] = fmaf(a.x, b.z, acc[0][2]); acc[0][3] = fmaf(a.x, b.w, acc[0][3]);
      acc[1][0] = fmaf(a.y, b.x, acc[1][0]); acc[1][1] = fmaf(a.y, b.y, acc[1][1]);
      acc[1][2] = fmaf(a.y, b.z, acc[1][2]); acc[1][3] = fmaf(a.y, b.w, acc[1][3]);
      acc[2][0] = fmaf(a.z, b.x, acc[2][0]); acc[2][1] = fmaf(a.z, b.y, acc[2][1]);
      acc[2][2] = fmaf(a.z, b.z, acc[2][2]); acc[2][3] = fmaf(a.z, b.w, acc[2][3]);
      acc[3][0] = fmaf(a.w, b.x, acc[3][0]); acc[3][1] = fmaf(a.w, b.y, acc[3][1]);
      acc[3][2] = fmaf(a.w, b.z, acc[3][2]); acc[3][3] = fmaf(a.w, b.w, acc[3][3]);
    }
    __syncthreads();
  }

  const int gm = blockIdx.y * 64 + m0;
  const int gn = blockIdx.x * 64 + n0;
  if (KS == 1) {
#pragma unroll
    for (int i = 0; i < 4; ++i) {
      float4 o;
      o.x = alpha * acc[i][0] + bias[gn + 0];
      o.y = alpha * acc[i][1] + bias[gn + 1];
      o.z = alpha * acc[i][2] + bias[gn + 2];
      o.w = alpha * acc[i][3] + bias[gn + 3];
      if (act == 1) {
        o.x = fmaxf(o.x, 0.f); o.y = fmaxf(o.y, 0.f);
        o.z = fmaxf(o.z, 0.f); o.w = fmaxf(o.w, 0.f);
      }
      *(float4*)&C[(size_t)(gm + i) * ldc + col0 + gn] = o;
    }
  } else {
    const int M = gridDim.y * 64, N = gridDim.x * 64;
#pragma unroll
    for (int i = 0; i < 4; ++i)
      *(float4*)&P[((size_t)blockIdx.z * M + gm + i) * N + gn] =
          make_float4(acc[i][0], acc[i][1], acc[i][2], acc[i][3]);
  }
}

__global__ __launch_bounds__(256) void gemm_reduce(
    const float* __restrict__ P, float* __restrict__ C,
    const float* __restrict__ bias, int M, int N, int ldc, int col0,
    float alpha, int act, int KS) {
  const int idx = blockIdx.x * 256 + threadIdx.x;
  if (idx >= M * N) return;
  const int m = idx / N, n = idx % N;
  float s = 0.f;
  for (int z = 0; z < KS; ++z) s += P[((size_t)z * M + m) * N + n];
  float v = alpha * s + bias[n];
  if (act == 1) v = fmaxf(v, 0.f);
  C[(size_t)m * ldc + col0 + n] = v;
}

// ======================= VQ =================================================
__global__ __launch_bounds__(256) void rowsq(const float* __restrict__ cb,
                                             float* __restrict__ csq) {
  const int row = blockIdx.x * 4 + (threadIdx.x >> 6);
  const int ln = threadIdx.x & 63;
  const float4 v = ((const float4*)(cb + (size_t)row * 256))[ln];
  float s = v.x * v.x + v.y * v.y + v.z * v.z + v.w * v.w;
#pragma unroll
  for (int off = 32; off > 0; off >>= 1) s += __shfl_down(s, off);
  if (ln == 0) csq[row] = s;
}

__global__ __launch_bounds__(256) void argmin_d2(const float* __restrict__ d2,
                                                 int* __restrict__ idx) {
  const int b = blockIdx.x, t = threadIdx.x;
  const float* row = d2 + (size_t)b * 8192;
  float best = 3.4e38f;
  int bi = 0x7fffffff;
  for (int k = t; k < 8192; k += 256) {
    const float v = row[k];
    if (v < best) { best = v; bi = k; }
  }
  __shared__ float bval[256];
  __shared__ int bidx[256];
  bval[t] = best;
  bidx[t] = bi;
  __syncthreads();
  for (int s = 128; s > 0; s >>= 1) {
    if (t < s) {
      const float ov = bval[t + s];
      const int oi = bidx[t + s];
      if (ov < bval[t] || (ov == bval[t] && oi < bidx[t])) {
        bval[t] = ov;
        bidx[t] = oi;
      }
    }
    __syncthreads();
  }
  if (t == 0) idx[b] = bidx[0];
}

__global__ __launch_bounds__(256) void vq_gather_loss(
    const float* __restrict__ ze, const float* __restrict__ cb,
    const int* __restrict__ idx, float* __restrict__ zq,
    float* __restrict__ lossacc) {
  const int b = blockIdx.x, d = threadIdx.x;
  const int i = b * 256 + d;
  const float q = cb[(size_t)idx[b] * 256 + d];
  zq[i] = q;
  const float df = ze[i] - q;
  float v = df * df;
  __shared__ float sh[256];
  sh[d] = v;
  __syncthreads();
  for (int s = 128; s > 0; s >>= 1) {
    if (d < s) sh[d] += sh[d + s];
    __syncthreads();
  }
  if (d == 0) atomicAdd(lossacc, sh[0]);
}

__global__ void write_loss(const float* __restrict__ lossacc,
                           float* __restrict__ out) {
  out[0] = 2.f * lossacc[0];
}

// ---------------------------------------------------------------------------
extern "C" void kernel_launch(void* const* d_in, const int* in_sizes, int n_in,
                              void* d_out, int out_size, void* d_ws,
                              size_t ws_size, hipStream_t stream) {
  const float* x = (const float*)d_in[0];
  const float* ew1 = (const float*)d_in[1];
  const float* eb1 = (const float*)d_in[2];
  const float* ew2 = (const float*)d_in[3];
  const float* eb2 = (const float*)d_in[4];
  const float* ew3 = (const float*)d_in[5];
  const float* eb3 = (const float*)d_in[6];
  const float* ew4 = (const float*)d_in[7];
  const float* eb4 = (const float*)d_in[8];
  const float* wmu = (const float*)d_in[9];
  const float* bmu = (const float*)d_in[10];
  const float* wcov = (const float*)d_in[11];
  const float* bcov = (const float*)d_in[12];
  const float* cb = (const float*)d_in[13];
  const float* wfc = (const float*)d_in[14];
  const float* bfc = (const float*)d_in[15];
  const float* wt1 = (const float*)d_in[16];
  const float* bt1 = (const float*)d_in[17];
  const float* wt2 = (const float*)d_in[18];
  const float* bt2 = (const float*)d_in[19];
  const float* wt3 = (const float*)d_in[20];
  const float* bt3 = (const float*)d_in[21];
  const float* wt31 = (const float*)d_in[22];
  const float* bt31 = (const float*)d_in[23];
  const float* wt4 = (const float*)d_in[24];
  const float* bt4 = (const float*)d_in[25];

  float* ws = (float*)d_ws;
  float* a1 = ws;               // NHWC [256,32,32,32]  (reused as g3)
  float* a2 = a1 + 8388608;     // NHWC [256,16,16,64]  (reused as g2)
  float* a3 = a2 + 4194304;     // NHWC [256,8,8,128]   (reused as g1)
  float* a4 = a3 + 2097152;     // NHWC [256,4,4,256]   (reused as g0)
  float* g31 = a4 + 1048576;    // NHWC [256,64,64,32]  33554432
  // scratch aliased inside g31 (all dead before t31 writes g31):
  float* d2 = g31;              // [256,8192]
  float* P = g31 + 2097152;     // 262144
  float* csq = g31 + 2359296;   // 8192
  float* wmuT = g31 + 2367488;  // 524288
  float* wcovT = g31 + 2891776; // 524288
  float* wfcT = g31 + 3416064;  // 1048576
  float* bfcT = g31 + 4464640;  // 4096
  float* wTc2 = g31 + 4468736;  // 18432
  float* wTc3 = g31 + 4487168;  // 73728
  float* wTc4 = g31 + 4560896;  // 294912 (ends 4855808 << 33554432)
  float* ze = g31 + 33554432;   // [256,256]
  float* zq = ze + 65536;
  float* stats = zq + 65536;    // 8 layers x 512
  float* lossacc = stats + 4096;
  int* idx = (int*)(lossacc + 4);
  float* wTt1 = lossacc + 4 + 256;  // 294912 (outside g31: live w/ g31)
  float* wTt2 = wTt1 + 294912;      // 73728
  float* wTt3 = wTt2 + 73728;       // 18432
  float* wTt31 = wTt3 + 18432;      // 9216
  float* g3 = a1;
  float* g2 = a2;
  float* g1 = a3;
  float* g0 = a4;

  float* st0 = stats + 0 * 512;
  float* st1 = stats + 1 * 512;
  float* st2 = stats + 2 * 512;
  float* st3 = stats + 3 * 512;
  float* st4 = stats + 4 * 512;
  float* st5 = stats + 5 * 512;
  float* st6 = stats + 6 * 512;
  float* st7 = stats + 7 * 512;

  hipMemsetAsync(stats, 0, (4096 + 8) * sizeof(float), stream);

  // ---- weight transposes (independent of activations) ----
  tr_convw<<<72, 256, 0, stream>>>(ew2, wTc2, 32, 64, 18432);
  tr_convw<<<288, 256, 0, stream>>>(ew3, wTc3, 64, 128, 73728);
  tr_convw<<<1152, 256, 0, stream>>>(ew4, wTc4, 128, 256, 294912);
  tr_convtw<<<1152, 256, 0, stream>>>(wt1, wTt1, 256, 128, 294912);
  tr_convtw<<<288, 256, 0, stream>>>(wt2, wTt2, 128, 64, 73728);
  tr_convtw<<<72, 256, 0, stream>>>(wt3, wTt3, 64, 32, 18432);
  tr_convtw<<<36, 256, 0, stream>>>(wt31, wTt31, 32, 32, 9216);
  tr_permk<<<2048, 256, 0, stream>>>(wmu, wmuT);
  tr_permk<<<2048, 256, 0, stream>>>(wcov, wcovT);
  tr_fcdec<<<4096, 256, 0, stream>>>(wfc, bfc, wfcT, bfcT);
  rowsq<<<2048, 256, 0, stream>>>(cb, csq);

  // ---- encoder ----
  conv1<<<dim3(256, 8), 256, 0, stream>>>(x, ew1, eb1, a1, st0);
  gemmconv<64, 64, 0, 32, 32, 64, true><<<dim3(1, 1024), 256, 0, stream>>>(
      a1, wTc2, eb2, st0, 1.f / (256.f * 1024.f), a2, st1);
  gemmconv<64, 64, 0, 16, 64, 128, true><<<dim3(2, 256), 256, 0, stream>>>(
      a2, wTc3, eb3, st1, 1.f / (256.f * 256.f), a3, st2);
  gemmconv<32, 64, 0, 8, 128, 256, true><<<dim3(4, 128), 256, 0, stream>>>(
      a3, wTc4, eb4, st2, 1.f / (256.f * 64.f), a4, st3);

  // ---- encoder FC (k-split, deterministic reduce) ----
  gemm_abt<<<dim3(2, 4, 8), 256, 0, stream>>>(a4, wmuT, nullptr, st3,
                                              1.f / 4096.f, nullptr, P, 4096,
                                              0, 0, 1.f, 0);
  gemm_reduce<<<128, 256, 0, stream>>>(P, ze, bmu, 256, 128, 256, 0, 1.f, 0, 8);
  gemm_abt<<<dim3(2, 4, 8), 256, 0, stream>>>(a4, wcovT, nullptr, st3,
                                              1.f / 4096.f, nullptr, P, 4096,
                                              0, 0, 1.f, 0);
  gemm_reduce<<<128, 256, 0, stream>>>(P, ze, bcov, 256, 128, 256, 128, 1.f, 1, 8);

  // ---- VQ ----
  gemm_abt<<<dim3(128, 4, 1), 256, 0, stream>>>(ze, cb, csq, nullptr, 0.f, d2,
                                                nullptr, 256, 8192, 0, -2.f, 0);
  argmin_d2<<<256, 256, 0, stream>>>(d2, idx);
  vq_gather_loss<<<256, 256, 0, stream>>>(ze, cb, idx, zq, lossacc);

  // ---- decoder FC (NHWC-permuted rows) ----
  gemm_abt<<<dim3(64, 4, 1), 256, 0, stream>>>(zq, wfcT, bfcT, nullptr, 0.f,
                                               g0, nullptr, 256, 4096, 0, 1.f, 0);

  // ---- decoder ----
  gemmconv<32, 64, 1, 4, 256, 128, false><<<dim3(2, 128, 4), 256, 0, stream>>>(
      g0, wTt1, bt1, nullptr, 0.f, g1, st4);
  gemmconv<64, 64, 1, 8, 128, 64, true><<<dim3(1, 256, 4), 256, 0, stream>>>(
      g1, wTt2, bt2, st4, 1.f / (256.f * 64.f), g2, st5);
  gemmconv<128, 32, 1, 16, 64, 32, true><<<dim3(1, 512, 4), 256, 0, stream>>>(
      g2, wTt3, bt3, st5, 1.f / (256.f * 256.f), g3, st6);
  gemmconv<128, 32, 1, 32, 32, 32, true><<<dim3(1, 2048, 4), 256, 0, stream>>>(
      g3, wTt31, bt31, st6, 1.f / (256.f * 1024.f), g31, st7);

  convt4_tanh<<<1024, 256, 0, stream>>>(g31, wt4, bt4, st7,
                                        1.f / (256.f * 4096.f), (float*)d_out);
  write_loss<<<1, 1, 0, stream>>>(lossacc, (float*)d_out + 3145728);
}

// Round 5
// 1062.320 us; speedup vs baseline: 10.0096x; 1.2664x over previous
//
#include <hip/hip_runtime.h>
#include <cmath>

// ---------------------------------------------------------------------------
// VQ-VAE forward, fp32. B=256, C=3, HW=64, D=256, K=8192, LAT=128
// R4: (a) loss-path bisect: a4 transposed back to NCHW and fc_enc GEMM uses
// raw wmu/wcov + k>>4 channel map (R2's proven-accurate path; tr_permk
// removed). (b) convt4_tanh rewritten as LDS-tiled (18x18x32 halo staged
// once, stride-36 padding, scalar-cached weights) to kill the 1.7 GB
// re-fetch. Everything else unchanged from R3.
// ---------------------------------------------------------------------------

#define EPS_BN 1e-5f

__device__ __forceinline__ float lrelu(float v) { return v >= 0.f ? v : 0.01f * v; }

// ======================= weight transposes (once per launch) ===============
// conv weights (COUT,CIN,3,3) -> wT[(t*CIN+ci)*COUT+co], t=ky*3+kx
__global__ __launch_bounds__(256) void tr_convw(const float* __restrict__ w,
                                                float* __restrict__ wT,
                                                int CIN, int COUT, int total) {
  int i = blockIdx.x * 256 + threadIdx.x;
  if (i >= total) return;
  int co = i % COUT;
  int tmp = i / COUT;
  int ci = tmp % CIN;
  int t = tmp / CIN;
  wT[i] = w[((size_t)co * CIN + ci) * 9 + t];
}

// convT weights (CIN,COUT,3,3) -> parity-concat wT, sizes {1,2,2,4}*CIN*COUT
__global__ __launch_bounds__(256) void tr_convtw(const float* __restrict__ w,
                                                 float* __restrict__ wT,
                                                 int CIN, int COUT, int total) {
  int i = blockIdx.x * 256 + threadIdx.x;
  if (i >= total) return;
  int u = i / (CIN * COUT);
  int rem = i % (CIN * COUT);
  int ci = rem / COUT, co = rem % COUT;
  int ky, kx;
  if (u == 0) { ky = 1; kx = 1; }
  else if (u <= 2) { ky = 1; kx = (u == 1) ? 0 : 2; }
  else if (u <= 4) { ky = (u == 3) ? 0 : 2; kx = 1; }
  else { int t = u - 5; ky = (t >> 1) ? 2 : 0; kx = (t & 1) ? 2 : 0; }
  wT[i] = w[((size_t)ci * COUT + co) * 9 + ky * 3 + kx];
}

// a4 NHWC [256,4,4,256] -> NCHW [256,256,4,4] (for the R2-proven fc path)
__global__ __launch_bounds__(256) void tr_a4(const float* __restrict__ in,
                                             float* __restrict__ out) {
  int i = blockIdx.x * 256 + threadIdx.x;  // 1048576
  int n = i >> 12, k = i & 4095;           // k = c*16 + s  (NCHW flat)
  out[i] = in[(size_t)(n << 12) + ((k & 15) << 8) + (k >> 4)];
}

// wfc [4096,256] + bfc: permute ROWS from (c,y,x) to (y,x,c)
__global__ __launch_bounds__(256) void tr_fcdec(const float* __restrict__ in,
                                                const float* __restrict__ bin,
                                                float* __restrict__ out,
                                                float* __restrict__ bout) {
  int i = blockIdx.x * 256 + threadIdx.x;  // 4096*256
  int k = i >> 8, d = i & 255;
  int kp = (k & 15) * 256 + (k >> 4);
  out[(size_t)kp * 256 + d] = in[i];
  if (d == 0) bout[kp] = bin[k];
}

// ======================= implicit-GEMM conv / convT ========================
template <int TM, int TN, int MODE, int IH, int CIN, int COUT, bool HASN>
__global__ __launch_bounds__(256) void gemmconv(
    const float* __restrict__ X, const float* __restrict__ WT,
    const float* __restrict__ bias, const float* __restrict__ st, float invN,
    float* __restrict__ Y, float* __restrict__ stOut) {
  constexpr int OH = (MODE == 0) ? IH / 2 : 2 * IH;
  constexpr int MR = TM / 16, NR = TN / 16;
  constexpr int LDA = TM + 8, LDB = TN + 8;
  __shared__ float As[16][LDA];
  __shared__ float Bs[16][LDB];
  __shared__ float nrm0[HASN ? CIN : 4], nrm1[HASN ? CIN : 4];
  __shared__ float redS[16][LDB], redQ[16][LDB];
  const int tid = threadIdx.x;
  if (HASN) {
    for (int c = tid; c < CIN; c += 256) {
      float m = st[c] * invN;
      float var = st[256 + c] * invN - m * m;
      float s = rsqrtf(var + EPS_BN);
      nrm0[c] = s;
      nrm1[c] = m * s;
    }
    __syncthreads();
  }
  int py = 0, px = 0, nx = 1, K = 9 * CIN;
  int dy0 = 0, dy1 = 0, dx0 = 0, dx1 = 0;
  const float* W = WT;
  if (MODE == 1) {
    const int pz = blockIdx.z;
    py = pz >> 1;
    px = pz & 1;
    nx = px ? 2 : 1;
    const int ny = py ? 2 : 1;
    if (py) { dy0 = 1; dy1 = 0; }
    if (px) { dx0 = 1; dx1 = 0; }
    K = ny * nx * CIN;
    const int pre[4] = {0, 1, 3, 5};
    W = WT + (size_t)pre[pz] * CIN * COUT;
  }
  const int gyTM = blockIdx.y * TM;
  const int gxTN = blockIdx.x * TN;

  constexpr int NCH = (TM * 4 + 255) / 256;
  int chRow[NCH], chQ4[NCH], chIY[NCH], chIX[NCH];
  size_t chNB[NCH];
  bool chV[NCH];
#pragma unroll
  for (int c = 0; c < NCH; ++c) {
    const int i = tid + c * 256;
    chV[c] = i < TM * 4;
    if (chV[c]) {
      const int row = i >> 2;
      chRow[c] = row;
      chQ4[c] = (i & 3) * 4;
      const int m = gyTM + row;
      if (MODE == 0) {
        const int ni = m / (OH * OH), r = m % (OH * OH);
        chNB[c] = (size_t)ni * IH * IH;
        chIY[c] = 2 * (r / OH) - 1;
        chIX[c] = 2 * (r % OH) - 1;
      } else {
        const int ni = m / (IH * IH), r = m % (IH * IH);
        chNB[c] = (size_t)ni * IH * IH;
        chIY[c] = r / IH;
        chIX[c] = r % IH;
      }
    }
  }
  const int m0 = (tid >> 4) * MR, n0 = (tid & 15) * NR;
  float acc[MR][NR];
#pragma unroll
  for (int i = 0; i < MR; ++i)
#pragma unroll
    for (int j = 0; j < NR; ++j) acc[i][j] = 0.f;

  for (int k0 = 0; k0 < K; k0 += 16) {
    const int t = k0 / CIN, ci0 = k0 - t * CIN;
    int ky, kx;
    if (MODE == 0) {
      ky = t / 3;
      kx = t - ky * 3;
    } else {
      const int kyi = t / nx, kxi = t - kyi * nx;
      ky = kyi ? dy1 : dy0;
      kx = kxi ? dx1 : dx0;
    }
#pragma unroll
    for (int c = 0; c < NCH; ++c) {
      if (chV[c]) {
        const int iy = chIY[c] + ky, ix = chIX[c] + kx;
        const bool ok =
            ((unsigned)iy < (unsigned)IH) && ((unsigned)ix < (unsigned)IH);
        float4 v = make_float4(0.f, 0.f, 0.f, 0.f);
        if (ok)
          v = *(const float4*)&X[(chNB[c] + iy * IH + ix) * CIN + ci0 + chQ4[c]];
        if (HASN) {
          const int cc = ci0 + chQ4[c];
          v.x = fmaf(v.x, nrm0[cc + 0], -nrm1[cc + 0]);
          v.y = fmaf(v.y, nrm0[cc + 1], -nrm1[cc + 1]);
          v.z = fmaf(v.z, nrm0[cc + 2], -nrm1[cc + 2]);
          v.w = fmaf(v.w, nrm0[cc + 3], -nrm1[cc + 3]);
        }
        const int kq = chQ4[c], rw = chRow[c];
        As[kq + 0][rw] = v.x;
        As[kq + 1][rw] = v.y;
        As[kq + 2][rw] = v.z;
        As[kq + 3][rw] = v.w;
      }
    }
#pragma unroll
    for (int c = 0; c < (TN * 4 + 255) / 256; ++c) {
      const int i = tid + c * 256;
      if (i < TN * 4) {
        const int kk = i / (TN / 4);
        const int nc = (i % (TN / 4)) * 4;
        *(float4*)&Bs[kk][nc] =
            *(const float4*)&W[(size_t)(k0 + kk) * COUT + gxTN + nc];
      }
    }
    __syncthreads();
#pragma unroll
    for (int kk = 0; kk < 16; ++kk) {
      float a[MR], b[NR];
      if constexpr (MR == 2) {
        const float2 av = *(const float2*)&As[kk][m0];
        a[0] = av.x; a[1] = av.y;
      } else if constexpr (MR == 4) {
        const float4 av = *(const float4*)&As[kk][m0];
        a[0] = av.x; a[1] = av.y; a[2] = av.z; a[3] = av.w;
      } else {
        const float4 av = *(const float4*)&As[kk][m0];
        const float4 aw = *(const float4*)&As[kk][m0 + 4];
        a[0] = av.x; a[1] = av.y; a[2] = av.z; a[3] = av.w;
        a[4] = aw.x; a[5] = aw.y; a[6] = aw.z; a[7] = aw.w;
      }
      if constexpr (NR == 2) {
        const float2 bv = *(const float2*)&Bs[kk][n0];
        b[0] = bv.x; b[1] = bv.y;
      } else {
        const float4 bv = *(const float4*)&Bs[kk][n0];
        b[0] = bv.x; b[1] = bv.y; b[2] = bv.z; b[3] = bv.w;
      }
#pragma unroll
      for (int i = 0; i < MR; ++i)
#pragma unroll
        for (int j = 0; j < NR; ++j) acc[i][j] = fmaf(a[i], b[j], acc[i][j]);
    }
    __syncthreads();
  }

  float bv[NR], colS[NR], colQ[NR];
#pragma unroll
  for (int j = 0; j < NR; ++j) {
    bv[j] = bias[gxTN + n0 + j];
    colS[j] = 0.f;
    colQ[j] = 0.f;
  }
#pragma unroll
  for (int i = 0; i < MR; ++i) {
    const int m = gyTM + m0 + i;
    float o[NR];
#pragma unroll
    for (int j = 0; j < NR; ++j) {
      o[j] = lrelu(acc[i][j] + bv[j]);
      colS[j] += o[j];
      colQ[j] += o[j] * o[j];
    }
    size_t addr;
    if (MODE == 0) {
      const int ni = m / (OH * OH), r = m % (OH * OH);
      addr = (((size_t)ni * OH + r / OH) * OH + r % OH) * COUT + gxTN + n0;
    } else {
      const int ni = m / (IH * IH), r = m % (IH * IH);
      const int oy = 2 * (r / IH) + py, ox = 2 * (r % IH) + px;
      addr = (((size_t)ni * OH + oy) * OH + ox) * COUT + gxTN + n0;
    }
    if constexpr (NR == 4)
      *(float4*)&Y[addr] = make_float4(o[0], o[1], o[2], o[3]);
    else
      *(float2*)&Y[addr] = make_float2(o[0], o[1]);
  }
  const int rgrp = tid >> 4;
#pragma unroll
  for (int j = 0; j < NR; ++j) {
    redS[rgrp][n0 + j] = colS[j];
    redQ[rgrp][n0 + j] = colQ[j];
  }
  __syncthreads();
  if (tid < TN) {
    float S = 0.f, Q = 0.f;
#pragma unroll
    for (int r = 0; r < 16; ++r) {
      S += redS[r][tid];
      Q += redQ[r][tid];
    }
    atomicAdd(&stOut[gxTN + tid], S);
    atomicAdd(&stOut[256 + gxTN + tid], Q);
  }
}

// ======================= conv1 (CIN=3), NCHW in -> NHWC out ================
__global__ __launch_bounds__(256) void conv1(
    const float* __restrict__ x, const float* __restrict__ w,
    const float* __restrict__ bias, float* __restrict__ y,
    float* __restrict__ st) {
  __shared__ float lw[4 * 3 * 12];
  __shared__ float red[2][4][4];
  const int tid = threadIdx.x;
  const int cog = blockIdx.y * 4;
  for (int i = tid; i < 4 * 27; i += 256) {
    int cor = i / 27, rem = i % 27;
    lw[(cor * 3 + rem / 9) * 12 + rem % 9] = w[cog * 27 + i];
  }
  __syncthreads();
  const int idx = blockIdx.x * 256 + tid;
  const int q = idx & 255;
  const int n = idx >> 8;
  const int qy = q >> 4, qx = q & 15;
  const int iy0 = 4 * qy - 1, ix0 = 4 * qx - 1;
  const float* xn = x + (size_t)n * 3 * 4096;
  bool okr[5], okc[5];
#pragma unroll
  for (int r = 0; r < 5; ++r) okr[r] = (unsigned)(iy0 + r) < 64u;
#pragma unroll
  for (int c = 0; c < 5; ++c) okc[c] = (unsigned)(ix0 + c) < 64u;

  float acc[4][4];
#pragma unroll
  for (int j = 0; j < 4; ++j) {
    const float b = bias[cog + j];
#pragma unroll
    for (int p = 0; p < 4; ++p) acc[j][p] = b;
  }
#pragma unroll
  for (int ci = 0; ci < 3; ++ci) {
    const float* xp = xn + ci * 4096;
    float v[5][5];
#pragma unroll
    for (int r = 0; r < 5; ++r)
#pragma unroll
      for (int c = 0; c < 5; ++c)
        v[r][c] = (okr[r] && okc[c]) ? xp[(iy0 + r) * 64 + ix0 + c] : 0.f;
#pragma unroll
    for (int j = 0; j < 4; ++j) {
      const float* wj = &lw[(j * 3 + ci) * 12];
#pragma unroll
      for (int dy = 0; dy < 2; ++dy)
#pragma unroll
        for (int dx = 0; dx < 2; ++dx)
#pragma unroll
          for (int ky = 0; ky < 3; ++ky)
#pragma unroll
            for (int kx = 0; kx < 3; ++kx)
              acc[j][dy * 2 + dx] = fmaf(v[2 * dy + ky][2 * dx + kx],
                                         wj[ky * 3 + kx], acc[j][dy * 2 + dx]);
    }
  }
  const int wv = tid >> 6, ln = tid & 63;
  float sS[4], sQ[4];
#pragma unroll
  for (int j = 0; j < 4; ++j) { sS[j] = 0.f; sQ[j] = 0.f; }
#pragma unroll
  for (int dy = 0; dy < 2; ++dy)
#pragma unroll
    for (int dx = 0; dx < 2; ++dx) {
      float4 o;
      o.x = lrelu(acc[0][dy * 2 + dx]);
      o.y = lrelu(acc[1][dy * 2 + dx]);
      o.z = lrelu(acc[2][dy * 2 + dx]);
      o.w = lrelu(acc[3][dy * 2 + dx]);
      *(float4*)&y[(((size_t)n * 32 + 2 * qy + dy) * 32 + 2 * qx + dx) * 32 +
                   cog] = o;
      sS[0] += o.x; sS[1] += o.y; sS[2] += o.z; sS[3] += o.w;
      sQ[0] += o.x * o.x; sQ[1] += o.y * o.y;
      sQ[2] += o.z * o.z; sQ[3] += o.w * o.w;
    }
#pragma unroll
  for (int j = 0; j < 4; ++j) {
    float s_ = sS[j], q_ = sQ[j];
#pragma unroll
    for (int off = 32; off > 0; off >>= 1) {
      s_ += __shfl_down(s_, off);
      q_ += __shfl_down(q_, off);
    }
    if (ln == 0) { red[0][wv][j] = s_; red[1][wv][j] = q_; }
  }
  __syncthreads();
  if (tid < 4) {
    const int j = tid;
    float S = red[0][0][j] + red[0][1][j] + red[0][2][j] + red[0][3][j];
    float Q = red[1][0][j] + red[1][1][j] + red[1][2][j] + red[1][3][j];
    atomicAdd(&st[cog + j], S);
    atomicAdd(&st[256 + cog + j], Q);
  }
}

// ======================= final convT 3x3 s1 p1 + tanh, LDS-tiled ===========
// block = (n, 16x16 output tile); stage normalized 18x18x32 halo in LDS
// (stride 36 -> b128-aligned, conflict-free); weights via uniform scalar
// loads (K$-cached). out NCHW.
__global__ __launch_bounds__(256) void convt4_tanh(
    const float* __restrict__ x, const float* __restrict__ w,
    const float* __restrict__ bias, const float* __restrict__ st, float invN,
    float* __restrict__ out) {
  __shared__ float tile[324 * 36];  // [px 0..323][ch 0..31] stride 36
  __shared__ float s0[32], s1[32];
  const int tid = threadIdx.x;
  for (int c = tid; c < 32; c += 256) {
    float m = st[c] * invN;
    float var = st[256 + c] * invN - m * m;
    float s = rsqrtf(var + EPS_BN);
    s0[c] = s;
    s1[c] = m * s;
  }
  __syncthreads();
  const int n = blockIdx.x >> 4;
  const int t16 = blockIdx.x & 15;
  const int oy0 = (t16 >> 2) * 16, ox0 = (t16 & 3) * 16;
  const float* xn = x + (size_t)n * 131072;
  for (int j = tid; j < 2592; j += 256) {
    const int px = j >> 3, cq = (j & 7) * 4;
    const int r = px / 18, c = px - r * 18;
    const int gy = oy0 - 1 + r, gx = ox0 - 1 + c;
    float4 v = make_float4(0.f, 0.f, 0.f, 0.f);
    if ((unsigned)gy < 64u && (unsigned)gx < 64u) {
      v = *(const float4*)&xn[(((size_t)gy << 6) + gx) * 32 + cq];
      v.x = fmaf(v.x, s0[cq + 0], -s1[cq + 0]);
      v.y = fmaf(v.y, s0[cq + 1], -s1[cq + 1]);
      v.z = fmaf(v.z, s0[cq + 2], -s1[cq + 2]);
      v.w = fmaf(v.w, s0[cq + 3], -s1[cq + 3]);
    }
    *(float4*)&tile[px * 36 + cq] = v;
  }
  __syncthreads();
  const int py = tid >> 4, pxx = tid & 15;
  float acc0 = bias[0], acc1 = bias[1], acc2 = bias[2];
#pragma unroll
  for (int t = 0; t < 9; ++t) {
    const int ky = t / 3, kx = t - ky * 3;
    const float* tp = &tile[((py + 2 - ky) * 18 + (pxx + 2 - kx)) * 36];
#pragma unroll
    for (int c8 = 0; c8 < 8; ++c8) {
      const float4 v = *(const float4*)&tp[c8 * 4];
#pragma unroll
      for (int u = 0; u < 4; ++u) {
        const float vi = (&v.x)[u];
        const float* wq = &w[(size_t)((c8 * 4 + u) * 3) * 9 + t];
        acc0 = fmaf(vi, wq[0], acc0);
        acc1 = fmaf(vi, wq[9], acc1);
        acc2 = fmaf(vi, wq[18], acc2);
      }
    }
  }
  const int oy = oy0 + py, ox = ox0 + pxx;
  float* op = out + (size_t)n * 3 * 4096 + oy * 64 + ox;
  op[0] = 1.f / (1.f + __expf(-2.f * acc0));
  op[4096] = 1.f / (1.f + __expf(-2.f * acc1));
  op[8192] = 1.f / (1.f + __expf(-2.f * acc2));
}

// ======================= dense GEMM (fc / VQ distance) =====================
// C[M,N] = alpha*A[M,K]*B[N,K]^T (+bias, act). Optional NCHW BN-norm on A
// (channel = k>>4, 256 channels) -- the R2-proven fc_enc path.
__global__ __launch_bounds__(256) void gemm_abt(
    const float* __restrict__ A, const float* __restrict__ B,
    const float* __restrict__ bias, const float* __restrict__ stA, float invN,
    float* __restrict__ C, float* __restrict__ P, int K, int ldc, int col0,
    float alpha, int act) {
  __shared__ float As[16][68];
  __shared__ float Bsh[16][68];
  __shared__ float nrm[2][256];
  const int tid = threadIdx.x;
  if (stA) {
    const int c = tid;
    float m = stA[c] * invN;
    float var = stA[256 + c] * invN - m * m;
    float s = rsqrtf(var + EPS_BN);
    nrm[0][c] = s;
    nrm[1][c] = m * s;
    __syncthreads();
  }
  const int lm = tid >> 2, lk = (tid & 3) << 2;
  const int KS = gridDim.z;
  const int kChunk = K / KS;
  const int kStart = blockIdx.z * kChunk;
  const float* Arow = A + (size_t)(blockIdx.y * 64 + lm) * K + lk;
  const float* Brow = B + (size_t)(blockIdx.x * 64 + lm) * K + lk;
  float acc[4][4] = {};
  const int m0 = (tid >> 4) << 2, n0 = (tid & 15) << 2;

  for (int k0 = kStart; k0 < kStart + kChunk; k0 += 16) {
    float4 av = *(const float4*)(Arow + k0);
    float4 bv = *(const float4*)(Brow + k0);
    if (stA) {
      const int ch = (k0 + lk) >> 4;
      const float s = nrm[0][ch], ms = nrm[1][ch];
      av.x = fmaf(av.x, s, -ms);
      av.y = fmaf(av.y, s, -ms);
      av.z = fmaf(av.z, s, -ms);
      av.w = fmaf(av.w, s, -ms);
    }
    As[lk + 0][lm] = av.x; As[lk + 1][lm] = av.y;
    As[lk + 2][lm] = av.z; As[lk + 3][lm] = av.w;
    Bsh[lk + 0][lm] = bv.x; Bsh[lk + 1][lm] = bv.y;
    Bsh[lk + 2][lm] = bv.z; Bsh[lk + 3][lm] = bv.w;
    __syncthreads();
#pragma unroll
    for (int kk = 0; kk < 16; ++kk) {
      const float4 a = *(const float4*)&As[kk][m0];
      const float4 b = *(const float4*)&Bsh[kk][n0];
      acc[0][0] = fmaf(a.x, b.x, acc[0][0]); acc[0][1] = fmaf(a.x, b.y, acc[0][1]);
      acc[0][2] = fmaf(a.x, b.z, acc[0][2]); acc[0][3] = fmaf(a.x, b.w, acc[0][3]);
      acc[1][0] = fmaf(a.y, b.x, acc[1][0]); acc[1][1] = fmaf(a.y, b.y, acc[1][1]);
      acc[1][2] = fmaf(a.y, b.z, acc[1][2]); acc[1][3] = fmaf(a.y, b.w, acc[1][3]);
      acc[2][0] = fmaf(a.z, b.x, acc[2][0]); acc[2][1] = fmaf(a.z, b.y, acc[2][1]);
      acc[2][2] = fmaf(a.z, b.z, acc[2][2]); acc[2][3] = fmaf(a.z, b.w, acc[2][3]);
      acc[3][0] = fmaf(a.w, b.x, acc[3][0]); acc[3][1] = fmaf(a.w, b.y, acc[3][1]);
      acc[3][2] = fmaf(a.w, b.z, acc[3][2]); acc[3][3] = fmaf(a.w, b.w, acc[3][3]);
    }
    __syncthreads();
  }

  const int gm = blockIdx.y * 64 + m0;
  const int gn = blockIdx.x * 64 + n0;
  if (KS == 1) {
#pragma unroll
    for (int i = 0; i < 4; ++i) {
      float4 o;
      o.x = alpha * acc[i][0] + bias[gn + 0];
      o.y = alpha * acc[i][1] + bias[gn + 1];
      o.z = alpha * acc[i][2] + bias[gn + 2];
      o.w = alpha * acc[i][3] + bias[gn + 3];
      if (act == 1) {
        o.x = fmaxf(o.x, 0.f); o.y = fmaxf(o.y, 0.f);
        o.z = fmaxf(o.z, 0.f); o.w = fmaxf(o.w, 0.f);
      }
      *(float4*)&C[(size_t)(gm + i) * ldc + col0 + gn] = o;
    }
  } else {
    const int M = gridDim.y * 64, N = gridDim.x * 64;
#pragma unroll
    for (int i = 0; i < 4; ++i)
      *(float4*)&P[((size_t)blockIdx.z * M + gm + i) * N + gn] =
          make_float4(acc[i][0], acc[i][1], acc[i][2], acc[i][3]);
  }
}

__global__ __launch_bounds__(256) void gemm_reduce(
    const float* __restrict__ P, float* __restrict__ C,
    const float* __restrict__ bias, int M, int N, int ldc, int col0,
    float alpha, int act, int KS) {
  const int idx = blockIdx.x * 256 + threadIdx.x;
  if (idx >= M * N) return;
  const int m = idx / N, n = idx % N;
  float s = 0.f;
  for (int z = 0; z < KS; ++z) s += P[((size_t)z * M + m) * N + n];
  float v = alpha * s + bias[n];
  if (act == 1) v = fmaxf(v, 0.f);
  C[(size_t)m * ldc + col0 + n] = v;
}

// ======================= VQ =================================================
__global__ __launch_bounds__(256) void rowsq(const float* __restrict__ cb,
                                             float* __restrict__ csq) {
  const int row = blockIdx.x * 4 + (threadIdx.x >> 6);
  const int ln = threadIdx.x & 63;
  const float4 v = ((const float4*)(cb + (size_t)row * 256))[ln];
  float s = v.x * v.x + v.y * v.y + v.z * v.z + v.w * v.w;
#pragma unroll
  for (int off = 32; off > 0; off >>= 1) s += __shfl_down(s, off);
  if (ln == 0) csq[row] = s;
}

__global__ __launch_bounds__(256) void argmin_d2(const float* __restrict__ d2,
                                                 int* __restrict__ idx) {
  const int b = blockIdx.x, t = threadIdx.x;
  const float* row = d2 + (size_t)b * 8192;
  float best = 3.4e38f;
  int bi = 0x7fffffff;
  for (int k = t; k < 8192; k += 256) {
    const float v = row[k];
    if (v < best) { best = v; bi = k; }
  }
  __shared__ float bval[256];
  __shared__ int bidx[256];
  bval[t] = best;
  bidx[t] = bi;
  __syncthreads();
  for (int s = 128; s > 0; s >>= 1) {
    if (t < s) {
      const float ov = bval[t + s];
      const int oi = bidx[t + s];
      if (ov < bval[t] || (ov == bval[t] && oi < bidx[t])) {
        bval[t] = ov;
        bidx[t] = oi;
      }
    }
    __syncthreads();
  }
  if (t == 0) idx[b] = bidx[0];
}

__global__ __launch_bounds__(256) void vq_gather_loss(
    const float* __restrict__ ze, const float* __restrict__ cb,
    const int* __restrict__ idx, float* __restrict__ zq,
    float* __restrict__ lossacc) {
  const int b = blockIdx.x, d = threadIdx.x;
  const int i = b * 256 + d;
  const float q = cb[(size_t)idx[b] * 256 + d];
  zq[i] = q;
  const float df = ze[i] - q;
  float v = df * df;
  __shared__ float sh[256];
  sh[d] = v;
  __syncthreads();
  for (int s = 128; s > 0; s >>= 1) {
    if (d < s) sh[d] += sh[d + s];
    __syncthreads();
  }
  if (d == 0) atomicAdd(lossacc, sh[0]);
}

__global__ void write_loss(const float* __restrict__ lossacc,
                           float* __restrict__ out) {
  out[0] = 2.f * lossacc[0];
}

// ---------------------------------------------------------------------------
extern "C" void kernel_launch(void* const* d_in, const int* in_sizes, int n_in,
                              void* d_out, int out_size, void* d_ws,
                              size_t ws_size, hipStream_t stream) {
  const float* x = (const float*)d_in[0];
  const float* ew1 = (const float*)d_in[1];
  const float* eb1 = (const float*)d_in[2];
  const float* ew2 = (const float*)d_in[3];
  const float* eb2 = (const float*)d_in[4];
  const float* ew3 = (const float*)d_in[5];
  const float* eb3 = (const float*)d_in[6];
  const float* ew4 = (const float*)d_in[7];
  const float* eb4 = (const float*)d_in[8];
  const float* wmu = (const float*)d_in[9];
  const float* bmu = (const float*)d_in[10];
  const float* wcov = (const float*)d_in[11];
  const float* bcov = (const float*)d_in[12];
  const float* cb = (const float*)d_in[13];
  const float* wfc = (const float*)d_in[14];
  const float* bfc = (const float*)d_in[15];
  const float* wt1 = (const float*)d_in[16];
  const float* bt1 = (const float*)d_in[17];
  const float* wt2 = (const float*)d_in[18];
  const float* bt2 = (const float*)d_in[19];
  const float* wt3 = (const float*)d_in[20];
  const float* bt3 = (const float*)d_in[21];
  const float* wt31 = (const float*)d_in[22];
  const float* bt31 = (const float*)d_in[23];
  const float* wt4 = (const float*)d_in[24];
  const float* bt4 = (const float*)d_in[25];

  float* ws = (float*)d_ws;
  float* a1 = ws;               // NHWC [256,32,32,32]  (reused as g3)
  float* a2 = a1 + 8388608;     // NHWC [256,16,16,64]  (reused as g2)
  float* a3 = a2 + 4194304;     // NHWC [256,8,8,128]   (reused as g1)
  float* a4 = a3 + 2097152;     // NHWC [256,4,4,256]   (reused as g0)
  float* g31 = a4 + 1048576;    // NHWC [256,64,64,32]  33554432
  // scratch aliased inside g31 (all dead before t31 writes g31):
  float* d2 = g31;              // [256,8192]
  float* P = g31 + 2097152;     // 262144
  float* csq = g31 + 2359296;   // 8192
  float* a4n = g31 + 2367488;   // NCHW a4 copy, 1048576
  float* wfcT = g31 + 3416064;  // 1048576
  float* bfcT = g31 + 4464640;  // 4096
  float* wTc2 = g31 + 4468736;  // 18432
  float* wTc3 = g31 + 4487168;  // 73728
  float* wTc4 = g31 + 4560896;  // 294912 (ends 4855808 << 33554432)
  float* ze = g31 + 33554432;   // [256,256]
  float* zq = ze + 65536;
  float* stats = zq + 65536;    // 8 layers x 512
  float* lossacc = stats + 4096;
  int* idx = (int*)(lossacc + 4);
  float* wTt1 = lossacc + 4 + 256;  // 294912
  float* wTt2 = wTt1 + 294912;      // 73728
  float* wTt3 = wTt2 + 73728;       // 18432
  float* wTt31 = wTt3 + 18432;      // 9216
  float* g3 = a1;
  float* g2 = a2;
  float* g1 = a3;
  float* g0 = a4;

  float* st0 = stats + 0 * 512;
  float* st1 = stats + 1 * 512;
  float* st2 = stats + 2 * 512;
  float* st3 = stats + 3 * 512;
  float* st4 = stats + 4 * 512;
  float* st5 = stats + 5 * 512;
  float* st6 = stats + 6 * 512;
  float* st7 = stats + 7 * 512;

  hipMemsetAsync(stats, 0, (4096 + 8) * sizeof(float), stream);

  // ---- weight transposes (independent of activations) ----
  tr_convw<<<72, 256, 0, stream>>>(ew2, wTc2, 32, 64, 18432);
  tr_convw<<<288, 256, 0, stream>>>(ew3, wTc3, 64, 128, 73728);
  tr_convw<<<1152, 256, 0, stream>>>(ew4, wTc4, 128, 256, 294912);
  tr_convtw<<<1152, 256, 0, stream>>>(wt1, wTt1, 256, 128, 294912);
  tr_convtw<<<288, 256, 0, stream>>>(wt2, wTt2, 128, 64, 73728);
  tr_convtw<<<72, 256, 0, stream>>>(wt3, wTt3, 64, 32, 18432);
  tr_convtw<<<36, 256, 0, stream>>>(wt31, wTt31, 32, 32, 9216);
  tr_fcdec<<<4096, 256, 0, stream>>>(wfc, bfc, wfcT, bfcT);
  rowsq<<<2048, 256, 0, stream>>>(cb, csq);

  // ---- encoder ----
  conv1<<<dim3(256, 8), 256, 0, stream>>>(x, ew1, eb1, a1, st0);
  gemmconv<64, 64, 0, 32, 32, 64, true><<<dim3(1, 1024), 256, 0, stream>>>(
      a1, wTc2, eb2, st0, 1.f / (256.f * 1024.f), a2, st1);
  gemmconv<64, 64, 0, 16, 64, 128, true><<<dim3(2, 256), 256, 0, stream>>>(
      a2, wTc3, eb3, st1, 1.f / (256.f * 256.f), a3, st2);
  gemmconv<32, 64, 0, 8, 128, 256, true><<<dim3(4, 128), 256, 0, stream>>>(
      a3, wTc4, eb4, st2, 1.f / (256.f * 64.f), a4, st3);
  tr_a4<<<4096, 256, 0, stream>>>(a4, a4n);

  // ---- encoder FC (R2-proven path: NCHW a4, raw wmu/wcov, ch=k>>4) ----
  gemm_abt<<<dim3(2, 4, 8), 256, 0, stream>>>(a4n, wmu, nullptr, st3,
                                              1.f / 4096.f, nullptr, P, 4096,
                                              0, 0, 1.f, 0);
  gemm_reduce<<<128, 256, 0, stream>>>(P, ze, bmu, 256, 128, 256, 0, 1.f, 0, 8);
  gemm_abt<<<dim3(2, 4, 8), 256, 0, stream>>>(a4n, wcov, nullptr, st3,
                                              1.f / 4096.f, nullptr, P, 4096,
                                              0, 0, 1.f, 0);
  gemm_reduce<<<128, 256, 0, stream>>>(P, ze, bcov, 256, 128, 256, 128, 1.f, 1, 8);

  // ---- VQ ----
  gemm_abt<<<dim3(128, 4, 1), 256, 0, stream>>>(ze, cb, csq, nullptr, 0.f, d2,
                                                nullptr, 256, 8192, 0, -2.f, 0);
  argmin_d2<<<256, 256, 0, stream>>>(d2, idx);
  vq_gather_loss<<<256, 256, 0, stream>>>(ze, cb, idx, zq, lossacc);

  // ---- decoder FC (NHWC-permuted rows) ----
  gemm_abt<<<dim3(64, 4, 1), 256, 0, stream>>>(zq, wfcT, bfcT, nullptr, 0.f,
                                               g0, nullptr, 256, 4096, 0, 1.f, 0);

  // ---- decoder ----
  gemmconv<32, 64, 1, 4, 256, 128, false><<<dim3(2, 128, 4), 256, 0, stream>>>(
      g0, wTt1, bt1, nullptr, 0.f, g1, st4);
  gemmconv<64, 64, 1, 8, 128, 64, true><<<dim3(1, 256, 4), 256, 0, stream>>>(
      g1, wTt2, bt2, st4, 1.f / (256.f * 64.f), g2, st5);
  gemmconv<128, 32, 1, 16, 64, 32, true><<<dim3(1, 512, 4), 256, 0, stream>>>(
      g2, wTt3, bt3, st5, 1.f / (256.f * 256.f), g3, st6);
  gemmconv<128, 32, 1, 32, 32, 32, true><<<dim3(1, 2048, 4), 256, 0, stream>>>(
      g3, wTt31, bt31, st6, 1.f / (256.f * 1024.f), g31, st7);

  convt4_tanh<<<4096, 256, 0, stream>>>(g31, wt4, bt4, st7,
                                        1.f / (256.f * 4096.f), (float*)d_out);
  write_loss<<<1, 1, 0, stream>>>(lossacc, (float*)d_out + 3145728);
}

// Round 6
// 880.853 us; speedup vs baseline: 12.0717x; 1.2060x over previous
//
#include <hip/hip_runtime.h>
#include <cmath>

// ---------------------------------------------------------------------------
// VQ-VAE forward, fp32. B=256, C=3, HW=64, D=256, K=8192, LAT=128
// R5: (a) CORRECTNESS: gemmconv A-stage normalized OOB zero-pad taps to
// -mean*invstd (norm was outside the bounds guard) -> boundary pollution in
// every BN-normalized conv; norm moved inside the guard. (b) convt4_tanh:
// weights loaded as contiguous wave-uniform float4 chunks per 4-channel
// block (hoisted, scalarizable) instead of 864 scattered in-loop loads.
// ---------------------------------------------------------------------------

#define EPS_BN 1e-5f

__device__ __forceinline__ float lrelu(float v) { return v >= 0.f ? v : 0.01f * v; }

// ======================= weight transposes (once per launch) ===============
// conv weights (COUT,CIN,3,3) -> wT[(t*CIN+ci)*COUT+co], t=ky*3+kx
__global__ __launch_bounds__(256) void tr_convw(const float* __restrict__ w,
                                                float* __restrict__ wT,
                                                int CIN, int COUT, int total) {
  int i = blockIdx.x * 256 + threadIdx.x;
  if (i >= total) return;
  int co = i % COUT;
  int tmp = i / COUT;
  int ci = tmp % CIN;
  int t = tmp / CIN;
  wT[i] = w[((size_t)co * CIN + ci) * 9 + t];
}

// convT weights (CIN,COUT,3,3) -> parity-concat wT, sizes {1,2,2,4}*CIN*COUT
__global__ __launch_bounds__(256) void tr_convtw(const float* __restrict__ w,
                                                 float* __restrict__ wT,
                                                 int CIN, int COUT, int total) {
  int i = blockIdx.x * 256 + threadIdx.x;
  if (i >= total) return;
  int u = i / (CIN * COUT);
  int rem = i % (CIN * COUT);
  int ci = rem / COUT, co = rem % COUT;
  int ky, kx;
  if (u == 0) { ky = 1; kx = 1; }
  else if (u <= 2) { ky = 1; kx = (u == 1) ? 0 : 2; }
  else if (u <= 4) { ky = (u == 3) ? 0 : 2; kx = 1; }
  else { int t = u - 5; ky = (t >> 1) ? 2 : 0; kx = (t & 1) ? 2 : 0; }
  wT[i] = w[((size_t)ci * COUT + co) * 9 + ky * 3 + kx];
}

// a4 NHWC [256,4,4,256] -> NCHW [256,256,4,4]
__global__ __launch_bounds__(256) void tr_a4(const float* __restrict__ in,
                                             float* __restrict__ out) {
  int i = blockIdx.x * 256 + threadIdx.x;  // 1048576
  int n = i >> 12, k = i & 4095;
  out[i] = in[(size_t)(n << 12) + ((k & 15) << 8) + (k >> 4)];
}

// wfc [4096,256] + bfc: permute ROWS from (c,y,x) to (y,x,c)
__global__ __launch_bounds__(256) void tr_fcdec(const float* __restrict__ in,
                                                const float* __restrict__ bin,
                                                float* __restrict__ out,
                                                float* __restrict__ bout) {
  int i = blockIdx.x * 256 + threadIdx.x;  // 4096*256
  int k = i >> 8, d = i & 255;
  int kp = (k & 15) * 256 + (k >> 4);
  out[(size_t)kp * 256 + d] = in[i];
  if (d == 0) bout[kp] = bin[k];
}

// ======================= implicit-GEMM conv / convT ========================
template <int TM, int TN, int MODE, int IH, int CIN, int COUT, bool HASN>
__global__ __launch_bounds__(256) void gemmconv(
    const float* __restrict__ X, const float* __restrict__ WT,
    const float* __restrict__ bias, const float* __restrict__ st, float invN,
    float* __restrict__ Y, float* __restrict__ stOut) {
  constexpr int OH = (MODE == 0) ? IH / 2 : 2 * IH;
  constexpr int MR = TM / 16, NR = TN / 16;
  constexpr int LDA = TM + 8, LDB = TN + 8;
  __shared__ float As[16][LDA];
  __shared__ float Bs[16][LDB];
  __shared__ float nrm0[HASN ? CIN : 4], nrm1[HASN ? CIN : 4];
  __shared__ float redS[16][LDB], redQ[16][LDB];
  const int tid = threadIdx.x;
  if (HASN) {
    for (int c = tid; c < CIN; c += 256) {
      float m = st[c] * invN;
      float var = st[256 + c] * invN - m * m;
      float s = rsqrtf(var + EPS_BN);
      nrm0[c] = s;
      nrm1[c] = m * s;
    }
    __syncthreads();
  }
  int py = 0, px = 0, nx = 1, K = 9 * CIN;
  int dy0 = 0, dy1 = 0, dx0 = 0, dx1 = 0;
  const float* W = WT;
  if (MODE == 1) {
    const int pz = blockIdx.z;
    py = pz >> 1;
    px = pz & 1;
    nx = px ? 2 : 1;
    const int ny = py ? 2 : 1;
    if (py) { dy0 = 1; dy1 = 0; }
    if (px) { dx0 = 1; dx1 = 0; }
    K = ny * nx * CIN;
    const int pre[4] = {0, 1, 3, 5};
    W = WT + (size_t)pre[pz] * CIN * COUT;
  }
  const int gyTM = blockIdx.y * TM;
  const int gxTN = blockIdx.x * TN;

  constexpr int NCH = (TM * 4 + 255) / 256;
  int chRow[NCH], chQ4[NCH], chIY[NCH], chIX[NCH];
  size_t chNB[NCH];
  bool chV[NCH];
#pragma unroll
  for (int c = 0; c < NCH; ++c) {
    const int i = tid + c * 256;
    chV[c] = i < TM * 4;
    if (chV[c]) {
      const int row = i >> 2;
      chRow[c] = row;
      chQ4[c] = (i & 3) * 4;
      const int m = gyTM + row;
      if (MODE == 0) {
        const int ni = m / (OH * OH), r = m % (OH * OH);
        chNB[c] = (size_t)ni * IH * IH;
        chIY[c] = 2 * (r / OH) - 1;
        chIX[c] = 2 * (r % OH) - 1;
      } else {
        const int ni = m / (IH * IH), r = m % (IH * IH);
        chNB[c] = (size_t)ni * IH * IH;
        chIY[c] = r / IH;
        chIX[c] = r % IH;
      }
    }
  }
  const int m0 = (tid >> 4) * MR, n0 = (tid & 15) * NR;
  float acc[MR][NR];
#pragma unroll
  for (int i = 0; i < MR; ++i)
#pragma unroll
    for (int j = 0; j < NR; ++j) acc[i][j] = 0.f;

  for (int k0 = 0; k0 < K; k0 += 16) {
    const int t = k0 / CIN, ci0 = k0 - t * CIN;
    int ky, kx;
    if (MODE == 0) {
      ky = t / 3;
      kx = t - ky * 3;
    } else {
      const int kyi = t / nx, kxi = t - kyi * nx;
      ky = kyi ? dy1 : dy0;
      kx = kxi ? dx1 : dx0;
    }
#pragma unroll
    for (int c = 0; c < NCH; ++c) {
      if (chV[c]) {
        const int iy = chIY[c] + ky, ix = chIX[c] + kx;
        const bool ok =
            ((unsigned)iy < (unsigned)IH) && ((unsigned)ix < (unsigned)IH);
        float4 v = make_float4(0.f, 0.f, 0.f, 0.f);
        if (ok) {
          v = *(const float4*)&X[(chNB[c] + iy * IH + ix) * CIN + ci0 + chQ4[c]];
          if (HASN) {
            // norm INSIDE the guard: OOB taps must stay exactly 0 (zero-pad)
            const int cc = ci0 + chQ4[c];
            v.x = fmaf(v.x, nrm0[cc + 0], -nrm1[cc + 0]);
            v.y = fmaf(v.y, nrm0[cc + 1], -nrm1[cc + 1]);
            v.z = fmaf(v.z, nrm0[cc + 2], -nrm1[cc + 2]);
            v.w = fmaf(v.w, nrm0[cc + 3], -nrm1[cc + 3]);
          }
        }
        const int kq = chQ4[c], rw = chRow[c];
        As[kq + 0][rw] = v.x;
        As[kq + 1][rw] = v.y;
        As[kq + 2][rw] = v.z;
        As[kq + 3][rw] = v.w;
      }
    }
#pragma unroll
    for (int c = 0; c < (TN * 4 + 255) / 256; ++c) {
      const int i = tid + c * 256;
      if (i < TN * 4) {
        const int kk = i / (TN / 4);
        const int nc = (i % (TN / 4)) * 4;
        *(float4*)&Bs[kk][nc] =
            *(const float4*)&W[(size_t)(k0 + kk) * COUT + gxTN + nc];
      }
    }
    __syncthreads();
#pragma unroll
    for (int kk = 0; kk < 16; ++kk) {
      float a[MR], b[NR];
      if constexpr (MR == 2) {
        const float2 av = *(const float2*)&As[kk][m0];
        a[0] = av.x; a[1] = av.y;
      } else if constexpr (MR == 4) {
        const float4 av = *(const float4*)&As[kk][m0];
        a[0] = av.x; a[1] = av.y; a[2] = av.z; a[3] = av.w;
      } else {
        const float4 av = *(const float4*)&As[kk][m0];
        const float4 aw = *(const float4*)&As[kk][m0 + 4];
        a[0] = av.x; a[1] = av.y; a[2] = av.z; a[3] = av.w;
        a[4] = aw.x; a[5] = aw.y; a[6] = aw.z; a[7] = aw.w;
      }
      if constexpr (NR == 2) {
        const float2 bv = *(const float2*)&Bs[kk][n0];
        b[0] = bv.x; b[1] = bv.y;
      } else {
        const float4 bv = *(const float4*)&Bs[kk][n0];
        b[0] = bv.x; b[1] = bv.y; b[2] = bv.z; b[3] = bv.w;
      }
#pragma unroll
      for (int i = 0; i < MR; ++i)
#pragma unroll
        for (int j = 0; j < NR; ++j) acc[i][j] = fmaf(a[i], b[j], acc[i][j]);
    }
    __syncthreads();
  }

  float bv[NR], colS[NR], colQ[NR];
#pragma unroll
  for (int j = 0; j < NR; ++j) {
    bv[j] = bias[gxTN + n0 + j];
    colS[j] = 0.f;
    colQ[j] = 0.f;
  }
#pragma unroll
  for (int i = 0; i < MR; ++i) {
    const int m = gyTM + m0 + i;
    float o[NR];
#pragma unroll
    for (int j = 0; j < NR; ++j) {
      o[j] = lrelu(acc[i][j] + bv[j]);
      colS[j] += o[j];
      colQ[j] += o[j] * o[j];
    }
    size_t addr;
    if (MODE == 0) {
      const int ni = m / (OH * OH), r = m % (OH * OH);
      addr = (((size_t)ni * OH + r / OH) * OH + r % OH) * COUT + gxTN + n0;
    } else {
      const int ni = m / (IH * IH), r = m % (IH * IH);
      const int oy = 2 * (r / IH) + py, ox = 2 * (r % IH) + px;
      addr = (((size_t)ni * OH + oy) * OH + ox) * COUT + gxTN + n0;
    }
    if constexpr (NR == 4)
      *(float4*)&Y[addr] = make_float4(o[0], o[1], o[2], o[3]);
    else
      *(float2*)&Y[addr] = make_float2(o[0], o[1]);
  }
  const int rgrp = tid >> 4;
#pragma unroll
  for (int j = 0; j < NR; ++j) {
    redS[rgrp][n0 + j] = colS[j];
    redQ[rgrp][n0 + j] = colQ[j];
  }
  __syncthreads();
  if (tid < TN) {
    float S = 0.f, Q = 0.f;
#pragma unroll
    for (int r = 0; r < 16; ++r) {
      S += redS[r][tid];
      Q += redQ[r][tid];
    }
    atomicAdd(&stOut[gxTN + tid], S);
    atomicAdd(&stOut[256 + gxTN + tid], Q);
  }
}

// ======================= conv1 (CIN=3), NCHW in -> NHWC out ================
__global__ __launch_bounds__(256) void conv1(
    const float* __restrict__ x, const float* __restrict__ w,
    const float* __restrict__ bias, float* __restrict__ y,
    float* __restrict__ st) {
  __shared__ float lw[4 * 3 * 12];
  __shared__ float red[2][4][4];
  const int tid = threadIdx.x;
  const int cog = blockIdx.y * 4;
  for (int i = tid; i < 4 * 27; i += 256) {
    int cor = i / 27, rem = i % 27;
    lw[(cor * 3 + rem / 9) * 12 + rem % 9] = w[cog * 27 + i];
  }
  __syncthreads();
  const int idx = blockIdx.x * 256 + tid;
  const int q = idx & 255;
  const int n = idx >> 8;
  const int qy = q >> 4, qx = q & 15;
  const int iy0 = 4 * qy - 1, ix0 = 4 * qx - 1;
  const float* xn = x + (size_t)n * 3 * 4096;
  bool okr[5], okc[5];
#pragma unroll
  for (int r = 0; r < 5; ++r) okr[r] = (unsigned)(iy0 + r) < 64u;
#pragma unroll
  for (int c = 0; c < 5; ++c) okc[c] = (unsigned)(ix0 + c) < 64u;

  float acc[4][4];
#pragma unroll
  for (int j = 0; j < 4; ++j) {
    const float b = bias[cog + j];
#pragma unroll
    for (int p = 0; p < 4; ++p) acc[j][p] = b;
  }
#pragma unroll
  for (int ci = 0; ci < 3; ++ci) {
    const float* xp = xn + ci * 4096;
    float v[5][5];
#pragma unroll
    for (int r = 0; r < 5; ++r)
#pragma unroll
      for (int c = 0; c < 5; ++c)
        v[r][c] = (okr[r] && okc[c]) ? xp[(iy0 + r) * 64 + ix0 + c] : 0.f;
#pragma unroll
    for (int j = 0; j < 4; ++j) {
      const float* wj = &lw[(j * 3 + ci) * 12];
#pragma unroll
      for (int dy = 0; dy < 2; ++dy)
#pragma unroll
        for (int dx = 0; dx < 2; ++dx)
#pragma unroll
          for (int ky = 0; ky < 3; ++ky)
#pragma unroll
            for (int kx = 0; kx < 3; ++kx)
              acc[j][dy * 2 + dx] = fmaf(v[2 * dy + ky][2 * dx + kx],
                                         wj[ky * 3 + kx], acc[j][dy * 2 + dx]);
    }
  }
  const int wv = tid >> 6, ln = tid & 63;
  float sS[4], sQ[4];
#pragma unroll
  for (int j = 0; j < 4; ++j) { sS[j] = 0.f; sQ[j] = 0.f; }
#pragma unroll
  for (int dy = 0; dy < 2; ++dy)
#pragma unroll
    for (int dx = 0; dx < 2; ++dx) {
      float4 o;
      o.x = lrelu(acc[0][dy * 2 + dx]);
      o.y = lrelu(acc[1][dy * 2 + dx]);
      o.z = lrelu(acc[2][dy * 2 + dx]);
      o.w = lrelu(acc[3][dy * 2 + dx]);
      *(float4*)&y[(((size_t)n * 32 + 2 * qy + dy) * 32 + 2 * qx + dx) * 32 +
                   cog] = o;
      sS[0] += o.x; sS[1] += o.y; sS[2] += o.z; sS[3] += o.w;
      sQ[0] += o.x * o.x; sQ[1] += o.y * o.y;
      sQ[2] += o.z * o.z; sQ[3] += o.w * o.w;
    }
#pragma unroll
  for (int j = 0; j < 4; ++j) {
    float s_ = sS[j], q_ = sQ[j];
#pragma unroll
    for (int off = 32; off > 0; off >>= 1) {
      s_ += __shfl_down(s_, off);
      q_ += __shfl_down(q_, off);
    }
    if (ln == 0) { red[0][wv][j] = s_; red[1][wv][j] = q_; }
  }
  __syncthreads();
  if (tid < 4) {
    const int j = tid;
    float S = red[0][0][j] + red[0][1][j] + red[0][2][j] + red[0][3][j];
    float Q = red[1][0][j] + red[1][1][j] + red[1][2][j] + red[1][3][j];
    atomicAdd(&st[cog + j], S);
    atomicAdd(&st[256 + cog + j], Q);
  }
}

// ======================= final convT 3x3 s1 p1 + tanh, LDS-tiled ===========
// block = (n, 16x16 output tile); normalized 18x18x32 halo staged in LDS.
// Weights: ci-block-of-4 outer loop; the block's 108 weights are one
// contiguous wave-uniform chunk -> 27 float4 loads hoisted to loop head.
__global__ __launch_bounds__(256) void convt4_tanh(
    const float* __restrict__ x, const float* __restrict__ w,
    const float* __restrict__ bias, const float* __restrict__ st, float invN,
    float* __restrict__ out) {
  __shared__ float tile[324 * 36];
  __shared__ float s0[32], s1[32];
  const int tid = threadIdx.x;
  for (int c = tid; c < 32; c += 256) {
    float m = st[c] * invN;
    float var = st[256 + c] * invN - m * m;
    float s = rsqrtf(var + EPS_BN);
    s0[c] = s;
    s1[c] = m * s;
  }
  __syncthreads();
  const int n = blockIdx.x >> 4;
  const int t16 = blockIdx.x & 15;
  const int oy0 = (t16 >> 2) * 16, ox0 = (t16 & 3) * 16;
  const float* xn = x + (size_t)n * 131072;
  for (int j = tid; j < 2592; j += 256) {
    const int px = j >> 3, cq = (j & 7) * 4;
    const int r = px / 18, c = px - r * 18;
    const int gy = oy0 - 1 + r, gx = ox0 - 1 + c;
    float4 v = make_float4(0.f, 0.f, 0.f, 0.f);
    if ((unsigned)gy < 64u && (unsigned)gx < 64u) {
      v = *(const float4*)&xn[(((size_t)gy << 6) + gx) * 32 + cq];
      v.x = fmaf(v.x, s0[cq + 0], -s1[cq + 0]);
      v.y = fmaf(v.y, s0[cq + 1], -s1[cq + 1]);
      v.z = fmaf(v.z, s0[cq + 2], -s1[cq + 2]);
      v.w = fmaf(v.w, s0[cq + 3], -s1[cq + 3]);
    }
    *(float4*)&tile[px * 36 + cq] = v;
  }
  __syncthreads();
  const int py = tid >> 4, pxx = tid & 15;
  float acc0 = bias[0], acc1 = bias[1], acc2 = bias[2];
  for (int cb4 = 0; cb4 < 8; ++cb4) {
    // weights for ci in [4cb4, 4cb4+4): 108 contiguous floats (uniform)
    float4 wv[27];
    const float4* wp = (const float4*)(w + cb4 * 108);
#pragma unroll
    for (int q = 0; q < 27; ++q) wv[q] = wp[q];
    const float* wr = (const float*)wv;  // wr[ciL*27 + co*9 + ky*3 + kx]
#pragma unroll
    for (int ky = 0; ky < 3; ++ky)
#pragma unroll
      for (int kx = 0; kx < 3; ++kx) {
        const float4 v = *(const float4*)
            &tile[((py + 2 - ky) * 18 + (pxx + 2 - kx)) * 36 + cb4 * 4];
        const int tt = ky * 3 + kx;
#pragma unroll
        for (int u = 0; u < 4; ++u) {
          const float vi = (&v.x)[u];
          acc0 = fmaf(vi, wr[u * 27 + tt], acc0);
          acc1 = fmaf(vi, wr[u * 27 + 9 + tt], acc1);
          acc2 = fmaf(vi, wr[u * 27 + 18 + tt], acc2);
        }
      }
  }
  const int oy = oy0 + py, ox = ox0 + pxx;
  float* op = out + (size_t)n * 3 * 4096 + oy * 64 + ox;
  op[0] = 1.f / (1.f + __expf(-2.f * acc0));
  op[4096] = 1.f / (1.f + __expf(-2.f * acc1));
  op[8192] = 1.f / (1.f + __expf(-2.f * acc2));
}

// ======================= dense GEMM (fc / VQ distance) =====================
__global__ __launch_bounds__(256) void gemm_abt(
    const float* __restrict__ A, const float* __restrict__ B,
    const float* __restrict__ bias, const float* __restrict__ stA, float invN,
    float* __restrict__ C, float* __restrict__ P, int K, int ldc, int col0,
    float alpha, int act) {
  __shared__ float As[16][68];
  __shared__ float Bsh[16][68];
  __shared__ float nrm[2][256];
  const int tid = threadIdx.x;
  if (stA) {
    const int c = tid;
    float m = stA[c] * invN;
    float var = stA[256 + c] * invN - m * m;
    float s = rsqrtf(var + EPS_BN);
    nrm[0][c] = s;
    nrm[1][c] = m * s;
    __syncthreads();
  }
  const int lm = tid >> 2, lk = (tid & 3) << 2;
  const int KS = gridDim.z;
  const int kChunk = K / KS;
  const int kStart = blockIdx.z * kChunk;
  const float* Arow = A + (size_t)(blockIdx.y * 64 + lm) * K + lk;
  const float* Brow = B + (size_t)(blockIdx.x * 64 + lm) * K + lk;
  float acc[4][4] = {};
  const int m0 = (tid >> 4) << 2, n0 = (tid & 15) << 2;

  for (int k0 = kStart; k0 < kStart + kChunk; k0 += 16) {
    float4 av = *(const float4*)(Arow + k0);
    float4 bv = *(const float4*)(Brow + k0);
    if (stA) {
      const int ch = (k0 + lk) >> 4;
      const float s = nrm[0][ch], ms = nrm[1][ch];
      av.x = fmaf(av.x, s, -ms);
      av.y = fmaf(av.y, s, -ms);
      av.z = fmaf(av.z, s, -ms);
      av.w = fmaf(av.w, s, -ms);
    }
    As[lk + 0][lm] = av.x; As[lk + 1][lm] = av.y;
    As[lk + 2][lm] = av.z; As[lk + 3][lm] = av.w;
    Bsh[lk + 0][lm] = bv.x; Bsh[lk + 1][lm] = bv.y;
    Bsh[lk + 2][lm] = bv.z; Bsh[lk + 3][lm] = bv.w;
    __syncthreads();
#pragma unroll
    for (int kk = 0; kk < 16; ++kk) {
      const float4 a = *(const float4*)&As[kk][m0];
      const float4 b = *(const float4*)&Bsh[kk][n0];
      acc[0][0] = fmaf(a.x, b.x, acc[0][0]); acc[0][1] = fmaf(a.x, b.y, acc[0][1]);
      acc[0][2] = fmaf(a.x, b.z, acc[0][2]); acc[0][3] = fmaf(a.x, b.w, acc[0][3]);
      acc[1][0] = fmaf(a.y, b.x, acc[1][0]); acc[1][1] = fmaf(a.y, b.y, acc[1][1]);
      acc[1][2] = fmaf(a.y, b.z, acc[1][2]); acc[1][3] = fmaf(a.y, b.w, acc[1][3]);
      acc[2][0] = fmaf(a.z, b.x, acc[2][0]); acc[2][1] = fmaf(a.z, b.y, acc[2][1]);
      acc[2][2] = fmaf(a.z, b.z, acc[2][2]); acc[2][3] = fmaf(a.z, b.w, acc[2][3]);
      acc[3][0] = fmaf(a.w, b.x, acc[3][0]); acc[3][1] = fmaf(a.w, b.y, acc[3][1]);
      acc[3][2] = fmaf(a.w, b.z, acc[3][2]); acc[3][3] = fmaf(a.w, b.w, acc[3][3]);
    }
    __syncthreads();
  }

  const int gm = blockIdx.y * 64 + m0;
  const int gn = blockIdx.x * 64 + n0;
  if (KS == 1) {
#pragma unroll
    for (int i = 0; i < 4; ++i) {
      float4 o;
      o.x = alpha * acc[i][0] + bias[gn + 0];
      o.y = alpha * acc[i][1] + bias[gn + 1];
      o.z = alpha * acc[i][2] + bias[gn + 2];
      o.w = alpha * acc[i][3] + bias[gn + 3];
      if (act == 1) {
        o.x = fmaxf(o.x, 0.f); o.y = fmaxf(o.y, 0.f);
        o.z = fmaxf(o.z, 0.f); o.w = fmaxf(o.w, 0.f);
      }
      *(float4*)&C[(size_t)(gm + i) * ldc + col0 + gn] = o;
    }
  } else {
    const int M = gridDim.y * 64, N = gridDim.x * 64;
#pragma unroll
    for (int i = 0; i < 4; ++i)
      *(float4*)&P[((size_t)blockIdx.z * M + gm + i) * N + gn] =
          make_float4(acc[i][0], acc[i][1], acc[i][2], acc[i][3]);
  }
}

__global__ __launch_bounds__(256) void gemm_reduce(
    const float* __restrict__ P, float* __restrict__ C,
    const float* __restrict__ bias, int M, int N, int ldc, int col0,
    float alpha, int act, int KS) {
  const int idx = blockIdx.x * 256 + threadIdx.x;
  if (idx >= M * N) return;
  const int m = idx / N, n = idx % N;
  float s = 0.f;
  for (int z = 0; z < KS; ++z) s += P[((size_t)z * M + m) * N + n];
  float v = alpha * s + bias[n];
  if (act == 1) v = fmaxf(v, 0.f);
  C[(size_t)m * ldc + col0 + n] = v;
}

// ======================= VQ =================================================
__global__ __launch_bounds__(256) void rowsq(const float* __restrict__ cb,
                                             float* __restrict__ csq) {
  const int row = blockIdx.x * 4 + (threadIdx.x >> 6);
  const int ln = threadIdx.x & 63;
  const float4 v = ((const float4*)(cb + (size_t)row * 256))[ln];
  float s = v.x * v.x + v.y * v.y + v.z * v.z + v.w * v.w;
#pragma unroll
  for (int off = 32; off > 0; off >>= 1) s += __shfl_down(s, off);
  if (ln == 0) csq[row] = s;
}

__global__ __launch_bounds__(256) void argmin_d2(const float* __restrict__ d2,
                                                 int* __restrict__ idx) {
  const int b = blockIdx.x, t = threadIdx.x;
  const float* row = d2 + (size_t)b * 8192;
  float best = 3.4e38f;
  int bi = 0x7fffffff;
  for (int k = t; k < 8192; k += 256) {
    const float v = row[k];
    if (v < best) { best = v; bi = k; }
  }
  __shared__ float bval[256];
  __shared__ int bidx[256];
  bval[t] = best;
  bidx[t] = bi;
  __syncthreads();
  for (int s = 128; s > 0; s >>= 1) {
    if (t < s) {
      const float ov = bval[t + s];
      const int oi = bidx[t + s];
      if (ov < bval[t] || (ov == bval[t] && oi < bidx[t])) {
        bval[t] = ov;
        bidx[t] = oi;
      }
    }
    __syncthreads();
  }
  if (t == 0) idx[b] = bidx[0];
}

__global__ __launch_bounds__(256) void vq_gather_loss(
    const float* __restrict__ ze, const float* __restrict__ cb,
    const int* __restrict__ idx, float* __restrict__ zq,
    float* __restrict__ lossacc) {
  const int b = blockIdx.x, d = threadIdx.x;
  const int i = b * 256 + d;
  const float q = cb[(size_t)idx[b] * 256 + d];
  zq[i] = q;
  const float df = ze[i] - q;
  float v = df * df;
  __shared__ float sh[256];
  sh[d] = v;
  __syncthreads();
  for (int s = 128; s > 0; s >>= 1) {
    if (d < s) sh[d] += sh[d + s];
    __syncthreads();
  }
  if (d == 0) atomicAdd(lossacc, sh[0]);
}

__global__ void write_loss(const float* __restrict__ lossacc,
                           float* __restrict__ out) {
  out[0] = 2.f * lossacc[0];
}

// ---------------------------------------------------------------------------
extern "C" void kernel_launch(void* const* d_in, const int* in_sizes, int n_in,
                              void* d_out, int out_size, void* d_ws,
                              size_t ws_size, hipStream_t stream) {
  const float* x = (const float*)d_in[0];
  const float* ew1 = (const float*)d_in[1];
  const float* eb1 = (const float*)d_in[2];
  const float* ew2 = (const float*)d_in[3];
  const float* eb2 = (const float*)d_in[4];
  const float* ew3 = (const float*)d_in[5];
  const float* eb3 = (const float*)d_in[6];
  const float* ew4 = (const float*)d_in[7];
  const float* eb4 = (const float*)d_in[8];
  const float* wmu = (const float*)d_in[9];
  const float* bmu = (const float*)d_in[10];
  const float* wcov = (const float*)d_in[11];
  const float* bcov = (const float*)d_in[12];
  const float* cb = (const float*)d_in[13];
  const float* wfc = (const float*)d_in[14];
  const float* bfc = (const float*)d_in[15];
  const float* wt1 = (const float*)d_in[16];
  const float* bt1 = (const float*)d_in[17];
  const float* wt2 = (const float*)d_in[18];
  const float* bt2 = (const float*)d_in[19];
  const float* wt3 = (const float*)d_in[20];
  const float* bt3 = (const float*)d_in[21];
  const float* wt31 = (const float*)d_in[22];
  const float* bt31 = (const float*)d_in[23];
  const float* wt4 = (const float*)d_in[24];
  const float* bt4 = (const float*)d_in[25];

  float* ws = (float*)d_ws;
  float* a1 = ws;               // NHWC [256,32,32,32]  (reused as g3)
  float* a2 = a1 + 8388608;     // NHWC [256,16,16,64]  (reused as g2)
  float* a3 = a2 + 4194304;     // NHWC [256,8,8,128]   (reused as g1)
  float* a4 = a3 + 2097152;     // NHWC [256,4,4,256]   (reused as g0)
  float* g31 = a4 + 1048576;    // NHWC [256,64,64,32]  33554432
  float* d2 = g31;              // [256,8192]
  float* P = g31 + 2097152;     // 262144
  float* csq = g31 + 2359296;   // 8192
  float* a4n = g31 + 2367488;   // NCHW a4 copy, 1048576
  float* wfcT = g31 + 3416064;  // 1048576
  float* bfcT = g31 + 4464640;  // 4096
  float* wTc2 = g31 + 4468736;  // 18432
  float* wTc3 = g31 + 4487168;  // 73728
  float* wTc4 = g31 + 4560896;  // 294912
  float* ze = g31 + 33554432;   // [256,256]
  float* zq = ze + 65536;
  float* stats = zq + 65536;    // 8 layers x 512
  float* lossacc = stats + 4096;
  int* idx = (int*)(lossacc + 4);
  float* wTt1 = lossacc + 4 + 256;  // 294912
  float* wTt2 = wTt1 + 294912;      // 73728
  float* wTt3 = wTt2 + 73728;       // 18432
  float* wTt31 = wTt3 + 18432;      // 9216
  float* g3 = a1;
  float* g2 = a2;
  float* g1 = a3;
  float* g0 = a4;

  float* st0 = stats + 0 * 512;
  float* st1 = stats + 1 * 512;
  float* st2 = stats + 2 * 512;
  float* st3 = stats + 3 * 512;
  float* st4 = stats + 4 * 512;
  float* st5 = stats + 5 * 512;
  float* st6 = stats + 6 * 512;
  float* st7 = stats + 7 * 512;

  hipMemsetAsync(stats, 0, (4096 + 8) * sizeof(float), stream);

  // ---- weight transposes (independent of activations) ----
  tr_convw<<<72, 256, 0, stream>>>(ew2, wTc2, 32, 64, 18432);
  tr_convw<<<288, 256, 0, stream>>>(ew3, wTc3, 64, 128, 73728);
  tr_convw<<<1152, 256, 0, stream>>>(ew4, wTc4, 128, 256, 294912);
  tr_convtw<<<1152, 256, 0, stream>>>(wt1, wTt1, 256, 128, 294912);
  tr_convtw<<<288, 256, 0, stream>>>(wt2, wTt2, 128, 64, 73728);
  tr_convtw<<<72, 256, 0, stream>>>(wt3, wTt3, 64, 32, 18432);
  tr_convtw<<<36, 256, 0, stream>>>(wt31, wTt31, 32, 32, 9216);
  tr_fcdec<<<4096, 256, 0, stream>>>(wfc, bfc, wfcT, bfcT);
  rowsq<<<2048, 256, 0, stream>>>(cb, csq);

  // ---- encoder ----
  conv1<<<dim3(256, 8), 256, 0, stream>>>(x, ew1, eb1, a1, st0);
  gemmconv<64, 64, 0, 32, 32, 64, true><<<dim3(1, 1024), 256, 0, stream>>>(
      a1, wTc2, eb2, st0, 1.f / (256.f * 1024.f), a2, st1);
  gemmconv<64, 64, 0, 16, 64, 128, true><<<dim3(2, 256), 256, 0, stream>>>(
      a2, wTc3, eb3, st1, 1.f / (256.f * 256.f), a3, st2);
  gemmconv<32, 64, 0, 8, 128, 256, true><<<dim3(4, 128), 256, 0, stream>>>(
      a3, wTc4, eb4, st2, 1.f / (256.f * 64.f), a4, st3);
  tr_a4<<<4096, 256, 0, stream>>>(a4, a4n);

  // ---- encoder FC (NCHW a4, raw wmu/wcov, ch=k>>4) ----
  gemm_abt<<<dim3(2, 4, 8), 256, 0, stream>>>(a4n, wmu, nullptr, st3,
                                              1.f / 4096.f, nullptr, P, 4096,
                                              0, 0, 1.f, 0);
  gemm_reduce<<<128, 256, 0, stream>>>(P, ze, bmu, 256, 128, 256, 0, 1.f, 0, 8);
  gemm_abt<<<dim3(2, 4, 8), 256, 0, stream>>>(a4n, wcov, nullptr, st3,
                                              1.f / 4096.f, nullptr, P, 4096,
                                              0, 0, 1.f, 0);
  gemm_reduce<<<128, 256, 0, stream>>>(P, ze, bcov, 256, 128, 256, 128, 1.f, 1, 8);

  // ---- VQ ----
  gemm_abt<<<dim3(128, 4, 1), 256, 0, stream>>>(ze, cb, csq, nullptr, 0.f, d2,
                                                nullptr, 256, 8192, 0, -2.f, 0);
  argmin_d2<<<256, 256, 0, stream>>>(d2, idx);
  vq_gather_loss<<<256, 256, 0, stream>>>(ze, cb, idx, zq, lossacc);

  // ---- decoder FC (NHWC-permuted rows) ----
  gemm_abt<<<dim3(64, 4, 1), 256, 0, stream>>>(zq, wfcT, bfcT, nullptr, 0.f,
                                               g0, nullptr, 256, 4096, 0, 1.f, 0);

  // ---- decoder ----
  gemmconv<32, 64, 1, 4, 256, 128, false><<<dim3(2, 128, 4), 256, 0, stream>>>(
      g0, wTt1, bt1, nullptr, 0.f, g1, st4);
  gemmconv<64, 64, 1, 8, 128, 64, true><<<dim3(1, 256, 4), 256, 0, stream>>>(
      g1, wTt2, bt2, st4, 1.f / (256.f * 64.f), g2, st5);
  gemmconv<128, 32, 1, 16, 64, 32, true><<<dim3(1, 512, 4), 256, 0, stream>>>(
      g2, wTt3, bt3, st5, 1.f / (256.f * 256.f), g3, st6);
  gemmconv<128, 32, 1, 32, 32, 32, true><<<dim3(1, 2048, 4), 256, 0, stream>>>(
      g3, wTt31, bt31, st6, 1.f / (256.f * 1024.f), g31, st7);

  convt4_tanh<<<4096, 256, 0, stream>>>(g31, wt4, bt4, st7,
                                        1.f / (256.f * 4096.f), (float*)d_out);
  write_loss<<<1, 1, 0, stream>>>(lossacc, (float*)d_out + 3145728);
}